// Round 9
// baseline (2247.180 us; speedup 1.0000x reference)
//
#include <hip/hip_runtime.h>
#include <math.h>

#define BATCH 32
#define TT    192
#define DM    512
#define CIN   64
#define SEQL  336
#define DFF   2048
#define NH    8
#define COF   0.1f
#define OUTN  (BATCH*TT*CIN)   // 393216
#define KEMB  208              // 192 conv + 4 mark + 12 zero-pad

typedef _Float16 h2_t __attribute__((ext_vector_type(2)));
union H2U { unsigned int u; h2_t h; };

typedef short bf16x8 __attribute__((ext_vector_type(8)));
typedef float f32x4 __attribute__((ext_vector_type(4)));
typedef unsigned int u32x4 __attribute__((ext_vector_type(4)));

__device__ __forceinline__ unsigned short f2bf(float v) {
  union { float f; unsigned int u; } a; a.f = v;
  unsigned int r = (a.u + 0x7fffu + ((a.u >> 16) & 1u)) >> 16;  // RNE
  return (unsigned short)r;
}

// async global->LDS 16B: lane l of the wave writes lds_base + l*16
__device__ __forceinline__ void gload16(const unsigned short* g, unsigned short* l) {
  __builtin_amdgcn_global_load_lds(
      (const __attribute__((address_space(1))) void*)g,
      (__attribute__((address_space(3))) void*)l, 16, 0, 0);
}

// signed 4x i8 dot product with i32 accumulate
__device__ __forceinline__ int sd4(unsigned int a, unsigned int b, int c) {
#if __has_builtin(__builtin_amdgcn_sdot4)
  return __builtin_amdgcn_sdot4((int)a, (int)b, c, false);
#else
  c += (int)(signed char)(a & 0xff) * (int)(signed char)(b & 0xff);
  c += (int)(signed char)((a >> 8) & 0xff) * (int)(signed char)((b >> 8) & 0xff);
  c += (int)(signed char)((a >> 16) & 0xff) * (int)(signed char)((b >> 16) & 0xff);
  c += (int)(signed char)(a >> 24) * (int)(signed char)(b >> 24);
  return c;
#endif
}

__device__ __forceinline__ int sd16(u32x4 w, u32x4 h, int acc) {
  acc = sd4(w[0], h[0], acc); acc = sd4(w[1], h[1], acc);
  acc = sd4(w[2], h[2], acc); acc = sd4(w[3], h[3], acc);
  return acc;
}

// quantize 4 floats (scale 127/8) into one packed i8x4 word
__device__ __forceinline__ unsigned int packq4(const float* hp) {
  int a = (int)rintf(hp[0] * 15.875f); a = a < -127 ? -127 : (a > 127 ? 127 : a);
  int b = (int)rintf(hp[1] * 15.875f); b = b < -127 ? -127 : (b > 127 ? 127 : b);
  int c = (int)rintf(hp[2] * 15.875f); c = c < -127 ? -127 : (c > 127 ? 127 : c);
  int d = (int)rintf(hp[3] * 15.875f); d = d < -127 ? -127 : (d > 127 ? 127 : d);
  return (unsigned int)((a & 0xff) | ((b & 0xff) << 8) | ((c & 0xff) << 16) |
                        ((d & 0xff) << 24));
}

// ---------------- small utility kernels ----------------

__global__ void zero_loss_kernel(float* loss) {
  if (threadIdx.x == 0) loss[0] = 0.f;
}

__global__ void zero_hqg_kernel(unsigned long long* p) {
  p[blockIdx.x * 256 + threadIdx.x] = 0ull;  // 32 blocks x 256 = 8192 qwords
}

__global__ void finalize_kernel(float* dout, const float* loss) {
  dout[OUTN] = loss[0] * (1.f / (float)OUTN);
}

// positional-encoding table, batch-independent: same formula as original (bit-identical)
__global__ void pe_table_kernel(float* __restrict__ peT) {
  int t = blockIdx.x, d = threadIdx.x;  // 192 x 512
  int i2 = (d >> 1) * 2;
  float freq = expf((float)i2 * (-9.210340371976184f / (float)DM));
  float ang = (float)t * freq;
  peT[(size_t)t * DM + d] = (d & 1) ? cosf(ang) : sinf(ang);
}

// Wemb[208][512]: rows 0..191 = conv_w (k=slot*64+c matches Xp layout),
// rows 192..195 = tf_w, rows 196..207 = 0
__global__ void build_wemb_kernel(const float* __restrict__ conv_w,
                                  const float* __restrict__ tf_w, float* __restrict__ Wemb) {
  int idx = blockIdx.x * 256 + threadIdx.x;  // 208*512 = 106496 -> 416 blocks
  int n = idx % DM, k = idx / DM;
  float v = 0.f;
  if (k < 192) v = conv_w[(size_t)k * DM + n];
  else if (k < 196) v = tf_w[(size_t)(k - 192) * DM + n];
  Wemb[idx] = v;
}

// Xp[row=b*TT+t][208] = [corrupt[b][t-1] | corrupt[b][t] | corrupt[b][t+1] | mark | 0]
__global__ void build_xp_kernel(const float* __restrict__ corrupt,
                                const float* __restrict__ ymark, float* __restrict__ Xp) {
  int idx = blockIdx.x * 256 + threadIdx.x;  // 6144*208 -> 4992 blocks
  int col = idx % KEMB, row = idx / KEMB;
  int b = row / TT, t = row % TT;
  float v;
  if (col < 64) {
    int tm = (t + TT - 1) % TT;
    v = corrupt[((size_t)b * TT + tm) * CIN + col];
  } else if (col < 128) {
    v = corrupt[((size_t)b * TT + t) * CIN + (col - 64)];
  } else if (col < 192) {
    int tp = (t + 1) % TT;
    v = corrupt[((size_t)b * TT + tp) * CIN + (col - 128)];
  } else if (col < 196) {
    v = ymark[((size_t)b * 240 + 48 + t) * 4 + (col - 192)];
  } else {
    v = 0.f;
  }
  Xp[idx] = v;
}

__global__ void stats_kernel(const float* __restrict__ x, float* __restrict__ means,
                             float* __restrict__ stdev) {
  int b = blockIdx.x, c = threadIdx.x;  // 64 threads
  const float* xb = x + (size_t)b * SEQL * CIN + c;
  float s = 0.f;
  for (int t = 0; t < SEQL; t++) s += xb[t * CIN];
  float mu = s * (1.f / SEQL);
  float s2 = 0.f;
  for (int t = 0; t < SEQL; t++) { float d = xb[t * CIN] - mu; s2 += d * d; }
  means[b * CIN + c] = mu;
  stdev[b * CIN + c] = sqrtf(s2 * (1.f / SEQL) + 1e-5f);
}

__global__ void pl1_kernel(const float* __restrict__ x, const float* __restrict__ means,
                           const float* __restrict__ stdev, const float* __restrict__ w,
                           const float* __restrict__ bias, float* __restrict__ pre) {
  int p = blockIdx.x, b = blockIdx.y, c = threadIdx.x;  // 64 threads
  float mu = means[b * CIN + c];
  float inv = 1.f / stdev[b * CIN + c];
  const float* xb = x + (size_t)b * SEQL * CIN + c;
  const float* wp = w + p * SEQL;
  float acc = 0.f;
  for (int t = 0; t < SEQL; t++) acc += (xb[t * CIN] - mu) * wp[t];
  pre[((size_t)b * TT + p) * CIN + c] = acc * inv + bias[p];
}

// pl2: corrupt f32 + bf16 copy into xcatB[:,0:64]
__global__ void pl2_kernel(const float* __restrict__ pre, const float* __restrict__ w,
                           const float* __restrict__ bias, float* __restrict__ out,
                           unsigned short* __restrict__ xc) {
  int q = blockIdx.x, b = blockIdx.y, c = threadIdx.x;  // 64 threads
  const float* pb = pre + (size_t)b * TT * CIN + c;
  const float* wq = w + q * TT;
  float acc = 0.f;
  for (int p = 0; p < TT; p++) acc += pb[p * CIN] * wq[p];
  float val = acc + bias[q];
  size_t r = (size_t)b * TT + q;
  out[r * CIN + c] = val;
  xc[r * 128 + c] = f2bf(val);
}

// ---------------- fp32 GEMM ----------------
// XC=1: write bf16 into xcatB[:,64:128] (proj). EMB=1: add peT[t][col], write
// emb f32 + embB bf16 (embed conv-as-GEMM).
template <int TB, int RELU, int XC, int EMB>
__global__ __launch_bounds__(256) void gemm_kernel(const float* __restrict__ A,
                                                   const float* __restrict__ B,
                                                   const float* __restrict__ bias,
                                                   float* __restrict__ C,
                                                   unsigned short* __restrict__ Cx,
                                                   const float* __restrict__ PE,
                                                   unsigned short* __restrict__ Cb2,
                                                   int M, int N, int K) {
  __shared__ float As[16][68];
  __shared__ float Bs[16][68];
  int tid = threadIdx.x;
  int bn = blockIdx.x * 64, bm = blockIdx.y * 64;
  int tx = tid & 15, ty = tid >> 4;
  int row0 = ty * 4, col0 = tx * 4;
  float acc[4][4] = {};
  for (int k0 = 0; k0 < K; k0 += 16) {
    {
      int m = tid >> 2, kq = (tid & 3) << 2;
      float4 av = *(const float4*)&A[(size_t)(bm + m) * K + k0 + kq];
      As[kq + 0][m] = av.x; As[kq + 1][m] = av.y; As[kq + 2][m] = av.z; As[kq + 3][m] = av.w;
    }
    if (TB) {
      int n = tid >> 2, kq = (tid & 3) << 2;
      float4 bv = *(const float4*)&B[(size_t)(bn + n) * K + k0 + kq];
      Bs[kq + 0][n] = bv.x; Bs[kq + 1][n] = bv.y; Bs[kq + 2][n] = bv.z; Bs[kq + 3][n] = bv.w;
    } else {
      int kk = tid >> 4, nq = (tid & 15) << 2;
      float4 bv = *(const float4*)&B[(size_t)(k0 + kk) * N + bn + nq];
      *(float4*)&Bs[kk][nq] = bv;
    }
    __syncthreads();
    #pragma unroll
    for (int k = 0; k < 16; k++) {
      float4 a4 = *(const float4*)&As[k][row0];
      float4 b4 = *(const float4*)&Bs[k][col0];
      float a[4] = {a4.x, a4.y, a4.z, a4.w};
      float bb[4] = {b4.x, b4.y, b4.z, b4.w};
      #pragma unroll
      for (int i = 0; i < 4; i++)
        #pragma unroll
        for (int j = 0; j < 4; j++) acc[i][j] += a[i] * bb[j];
    }
    __syncthreads();
  }
  float bv[4] = {0.f, 0.f, 0.f, 0.f};
  if (bias) *(float4*)bv = *(const float4*)&bias[bn + col0];
  #pragma unroll
  for (int i = 0; i < 4; i++) {
    int row = bm + row0 + i;
    float pe[4] = {0.f, 0.f, 0.f, 0.f};
    if (EMB) {
      int t = row % TT;
      *(float4*)pe = *(const float4*)&PE[(size_t)t * DM + bn + col0];
    }
    float ov[4];
    #pragma unroll
    for (int j = 0; j < 4; j++) {
      float v = acc[i][j] + bv[j];
      if (EMB) v += pe[j];
      if (RELU) v = fmaxf(v, 0.f);
      ov[j] = v;
    }
    if (XC) {
      unsigned short xv[4];
      #pragma unroll
      for (int j = 0; j < 4; j++) xv[j] = f2bf(ov[j]);
      *(uint2*)&Cx[(size_t)row * 128 + 64 + bn + col0] = *(uint2*)xv;
    } else {
      *(float4*)&C[(size_t)row * N + bn + col0] = *(float4*)ov;
      if (EMB) {
        unsigned short xv[4];
        #pragma unroll
        for (int j = 0; j < 4; j++) xv[j] = f2bf(ov[j]);
        *(uint2*)&Cb2[(size_t)row * N + bn + col0] = *(uint2*)xv;
      }
    }
  }
}

// ---------------- bf16 MFMA GEMM (bf16 A, bf16 Bt [N][K]) ----------------
template <int RELU, int WF32, int WBF16>
__global__ __launch_bounds__(256) void gemm_bf16_kernel(
    const unsigned short* __restrict__ A, const unsigned short* __restrict__ Bt,
    const float* __restrict__ bias, float* __restrict__ C, unsigned short* __restrict__ Cb,
    int M, int N, int K) {
  __shared__ __align__(16) unsigned short As[128 * 32];
  __shared__ __align__(16) unsigned short Bs[128 * 32];
  int tid = threadIdx.x;
  int bm = blockIdx.y * 128, bn = blockIdx.x * 128;
  int wave = tid >> 6, lane = tid & 63;
  int wm = (wave >> 1) * 64, wn = (wave & 1) * 64;
  int r15 = lane & 15, q = lane >> 4;
  f32x4 acc[4][4] = {};
  int srow = wave * 32 + (lane >> 2);
  int scol = (lane & 3) * 8;
  for (int k0 = 0; k0 < K; k0 += 32) {
    gload16(&A[(size_t)(bm + srow) * K + k0 + scol], &As[(wave * 32) * 32]);
    gload16(&A[(size_t)(bm + srow + 16) * K + k0 + scol], &As[(wave * 32 + 16) * 32]);
    gload16(&Bt[(size_t)(bn + srow) * K + k0 + scol], &Bs[(wave * 32) * 32]);
    gload16(&Bt[(size_t)(bn + srow + 16) * K + k0 + scol], &Bs[(wave * 32 + 16) * 32]);
    __syncthreads();
    bf16x8 af[4], bfr[4];
    #pragma unroll
    for (int mi = 0; mi < 4; mi++)
      af[mi] = *(const bf16x8*)&As[(wm + mi * 16 + r15) * 32 + q * 8];
    #pragma unroll
    for (int ni = 0; ni < 4; ni++)
      bfr[ni] = *(const bf16x8*)&Bs[(wn + ni * 16 + r15) * 32 + q * 8];
    #pragma unroll
    for (int mi = 0; mi < 4; mi++)
      #pragma unroll
      for (int ni = 0; ni < 4; ni++)
        acc[mi][ni] =
            __builtin_amdgcn_mfma_f32_16x16x32_bf16(af[mi], bfr[ni], acc[mi][ni], 0, 0, 0);
    __syncthreads();
  }
  #pragma unroll
  for (int mi = 0; mi < 4; mi++) {
    #pragma unroll
    for (int ni = 0; ni < 4; ni++) {
      int col = bn + wn + ni * 16 + r15;
      float bv = bias ? bias[col] : 0.f;
      #pragma unroll
      for (int v = 0; v < 4; v++) {
        int row = bm + wm + mi * 16 + q * 4 + v;
        float val = acc[mi][ni][v] + bv;
        if (RELU) val = fmaxf(val, 0.f);
        if (WF32) C[(size_t)row * N + col] = val;
        if (WBF16) Cb[(size_t)row * N + col] = f2bf(val);
      }
    }
  }
}

// K-split partial GEMM for the AXPY path: grid (4, M/128)
__global__ __launch_bounds__(256) void axpy_partial_kernel(
    const unsigned short* __restrict__ A, const unsigned short* __restrict__ Bt,
    float* __restrict__ P, int M, int K) {
  __shared__ __align__(16) unsigned short As[128 * 32];
  __shared__ __align__(16) unsigned short Bs[128 * 32];
  int tid = threadIdx.x;
  int kq = blockIdx.x;
  int bm = blockIdx.y * 128;
  int wave = tid >> 6, lane = tid & 63;
  int wm = (wave >> 1) * 64, wn = (wave & 1) * 64;
  int r15 = lane & 15, q = lane >> 4;
  f32x4 acc[4][4] = {};
  int srow = wave * 32 + (lane >> 2);
  int scol = (lane & 3) * 8;
  int kbeg = kq * (K >> 2), kend = (kq + 1) * (K >> 2);
  for (int k0 = kbeg; k0 < kend; k0 += 32) {
    gload16(&A[(size_t)(bm + srow) * K + k0 + scol], &As[(wave * 32) * 32]);
    gload16(&A[(size_t)(bm + srow + 16) * K + k0 + scol], &As[(wave * 32 + 16) * 32]);
    gload16(&Bt[(size_t)srow * K + k0 + scol], &Bs[(wave * 32) * 32]);
    gload16(&Bt[(size_t)(srow + 16) * K + k0 + scol], &Bs[(wave * 32 + 16) * 32]);
    __syncthreads();
    bf16x8 af[4], bfr[4];
    #pragma unroll
    for (int mi = 0; mi < 4; mi++)
      af[mi] = *(const bf16x8*)&As[(wm + mi * 16 + r15) * 32 + q * 8];
    #pragma unroll
    for (int ni = 0; ni < 4; ni++)
      bfr[ni] = *(const bf16x8*)&Bs[(wn + ni * 16 + r15) * 32 + q * 8];
    #pragma unroll
    for (int mi = 0; mi < 4; mi++)
      #pragma unroll
      for (int ni = 0; ni < 4; ni++)
        acc[mi][ni] =
            __builtin_amdgcn_mfma_f32_16x16x32_bf16(af[mi], bfr[ni], acc[mi][ni], 0, 0, 0);
    __syncthreads();
  }
  #pragma unroll
  for (int mi = 0; mi < 4; mi++) {
    #pragma unroll
    for (int ni = 0; ni < 4; ni++) {
      int col = wn + ni * 16 + r15;
      if (col < 64) {
        #pragma unroll
        for (int v = 0; v < 4; v++) {
          int row = bm + wm + mi * 16 + q * 4 + v;
          P[(size_t)kq * OUTN + (size_t)row * 64 + col] = acc[mi][ni][v];
        }
      }
    }
  }
}

// tiled transpose-pack: dst[n*K + k] = bf16(src[k*N + n]); coalesced both sides
__global__ __launch_bounds__(256) void pack_transpose_bf16_kernel(
    const float* __restrict__ src, unsigned short* __restrict__ dst, int K, int N) {
  __shared__ unsigned short tile[64][65];
  int kb = blockIdx.x * 64, nb = blockIdx.y * 64;
  int tid = threadIdx.x;
  int tn = tid & 63, tk = tid >> 6;  // 4 rows per pass
  #pragma unroll
  for (int i = 0; i < 16; i++) {
    int k = tk + i * 4;
    tile[k][tn] = f2bf(src[(size_t)(kb + k) * N + nb + tn]);
  }
  __syncthreads();
  int tk2 = tid & 63, tn2 = tid >> 6;
  #pragma unroll
  for (int i = 0; i < 16; i++) {
    int n = tn2 + i * 4;
    dst[(size_t)(nb + n) * K + kb + tk2] = tile[tk2][n];
  }
}

__global__ void pack_bf16_kernel(const float* __restrict__ src, unsigned short* __restrict__ dst,
                                 int n) {
  int idx = blockIdx.x * 256 + threadIdx.x;
  if (idx < n) dst[idx] = f2bf(src[idx]);
}

// WxProjB[n][k] (n<128, k<1536) = n<64 ? bf16(wih[k*128 + n]) : 0
__global__ void pack_wxproj_kernel(const float* __restrict__ wih,
                                   unsigned short* __restrict__ dst) {
  int idx = blockIdx.x * 256 + threadIdx.x;  // 128*1536
  int k = idx % 1536, n = idx / 1536;
  float v = (n < 64) ? wih[(size_t)k * 128 + n] : 0.f;
  dst[idx] = f2bf(v);
}

__global__ void concat_qkv_bias_kernel(const float* __restrict__ bq, const float* __restrict__ bk,
                                       const float* __restrict__ bv, float* __restrict__ dst) {
  int l = blockIdx.y;
  int i = blockIdx.x * 256 + threadIdx.x;  // < 1536
  float v = (i < 512) ? bq[l * 512 + i]
                      : ((i < 1024) ? bk[l * 512 + i - 512] : bv[l * 512 + i - 1024]);
  dst[l * 1536 + i] = v;
}

// ---------------- MFMA attention: grid (NH, BATCH, 3) ----------------
// R8 counters: 256 blocks x 4 waves = 12.5% occupancy, 3 serial Q-tiles/wave ->
// latency-bound. z-split: each block handles 4 of 12 Q-tiles (one per wave),
// 3x parallelism, 3x shorter serial tail. K/V staging duplicated (L2-resident).
__global__ __launch_bounds__(256) void attention_mfma_kernel(
    const unsigned short* __restrict__ qkv, unsigned short* __restrict__ attnO) {
  __shared__ __align__(16) unsigned short Ks[192 * 72];
  __shared__ __align__(16) unsigned short Vt[64 * 200];
  __shared__ __align__(16) float Ps[4][16 * 36];
  int h = blockIdx.x, b = blockIdx.y;
  int tid = threadIdx.x, wave = tid >> 6, lane = tid & 63;
  int m = lane & 15, q = lane >> 4;
  const unsigned short* Qg = qkv + (size_t)b * TT * 1536 + h * 64;
  const unsigned short* Kg = Qg + 512;
  const unsigned short* Vg = Qg + 1024;
  for (int idx = tid; idx < 192 * 8; idx += 256) {
    int s = idx >> 3, ch = (idx & 7) * 8;
    *(uint4*)&Ks[s * 72 + ch] = *(const uint4*)&Kg[(size_t)s * 1536 + ch];
  }
  for (int idx = tid; idx < 96 * 8; idx += 256) {
    int sp = idx >> 3, co = (idx & 7) * 8;
    uint4 v0 = *(const uint4*)&Vg[(size_t)(2 * sp) * 1536 + co];
    uint4 v1 = *(const uint4*)&Vg[(size_t)(2 * sp + 1) * 1536 + co];
    const unsigned short* e0 = (const unsigned short*)&v0;
    const unsigned short* e1 = (const unsigned short*)&v1;
    unsigned int* vtw = (unsigned int*)Vt;
    #pragma unroll
    for (int u = 0; u < 8; u++)
      vtw[(co + u) * 100 + sp] = (unsigned int)e0[u] | ((unsigned int)e1[u] << 16);
  }
  __syncthreads();
  float* ps = Ps[wave];
  {
    int tile = blockIdx.z * 4 + wave;  // one tile per wave
    int t0 = tile * 16;
    bf16x8 qf0 = *(const bf16x8*)&Qg[(size_t)(t0 + m) * 1536 + q * 8];
    bf16x8 qf1 = *(const bf16x8*)&Qg[(size_t)(t0 + m) * 1536 + 32 + q * 8];
    f32x4 S[12];
    #pragma unroll
    for (int nt = 0; nt < 12; nt++) {
      bf16x8 kf0 = *(const bf16x8*)&Ks[(nt * 16 + m) * 72 + q * 8];
      bf16x8 kf1 = *(const bf16x8*)&Ks[(nt * 16 + m) * 72 + 32 + q * 8];
      f32x4 a = {0.f, 0.f, 0.f, 0.f};
      a = __builtin_amdgcn_mfma_f32_16x16x32_bf16(qf0, kf0, a, 0, 0, 0);
      a = __builtin_amdgcn_mfma_f32_16x16x32_bf16(qf1, kf1, a, 0, 0, 0);
      S[nt] = a;
    }
    float mx[4] = {-1e30f, -1e30f, -1e30f, -1e30f};
    #pragma unroll
    for (int nt = 0; nt < 12; nt++)
      #pragma unroll
      for (int v = 0; v < 4; v++) {
        S[nt][v] *= 0.125f;
        mx[v] = fmaxf(mx[v], S[nt][v]);
      }
    #pragma unroll
    for (int d = 1; d < 16; d <<= 1) {
      #pragma unroll
      for (int v = 0; v < 4; v++) mx[v] = fmaxf(mx[v], __shfl_xor(mx[v], d));
    }
    float sm[4] = {0.f, 0.f, 0.f, 0.f};
    #pragma unroll
    for (int nt = 0; nt < 12; nt++)
      #pragma unroll
      for (int v = 0; v < 4; v++) {
        float e = __expf(S[nt][v] - mx[v]);
        S[nt][v] = e;
        sm[v] += e;
      }
    #pragma unroll
    for (int d = 1; d < 16; d <<= 1) {
      #pragma unroll
      for (int v = 0; v < 4; v++) sm[v] += __shfl_xor(sm[v], d);
    }
    float inv[4];
    #pragma unroll
    for (int v = 0; v < 4; v++) inv[v] = 1.f / sm[v];
    f32x4 o[4] = {};
    for (int kc = 0; kc < 6; kc++) {
      asm volatile("s_waitcnt lgkmcnt(0)" ::: "memory");
      #pragma unroll
      for (int half = 0; half < 2; half++) {
        int nt = 2 * kc + half;
        #pragma unroll
        for (int v = 0; v < 4; v++) ps[(q * 4 + v) * 36 + half * 16 + m] = S[nt][v];
      }
      asm volatile("s_waitcnt lgkmcnt(0)" ::: "memory");
      float4 p0 = *(const float4*)&ps[m * 36 + q * 8];
      float4 p1 = *(const float4*)&ps[m * 36 + q * 8 + 4];
      unsigned short tmp[8];
      tmp[0] = f2bf(p0.x); tmp[1] = f2bf(p0.y); tmp[2] = f2bf(p0.z); tmp[3] = f2bf(p0.w);
      tmp[4] = f2bf(p1.x); tmp[5] = f2bf(p1.y); tmp[6] = f2bf(p1.z); tmp[7] = f2bf(p1.w);
      bf16x8 pf = *(bf16x8*)tmp;
      #pragma unroll
      for (int nt2 = 0; nt2 < 4; nt2++) {
        bf16x8 vf = *(const bf16x8*)&Vt[(nt2 * 16 + m) * 200 + kc * 32 + q * 8];
        o[nt2] = __builtin_amdgcn_mfma_f32_16x16x32_bf16(pf, vf, o[nt2], 0, 0, 0);
      }
    }
    #pragma unroll
    for (int nt2 = 0; nt2 < 4; nt2++)
      #pragma unroll
      for (int v = 0; v < 4; v++) {
        size_t row = (size_t)b * TT + t0 + q * 4 + v;
        attnO[row * 512 + h * 64 + nt2 * 16 + m] = f2bf(o[nt2][v] * inv[v]);
      }
  }
}

// ---------------- layernorm with residual, in-place on x; bf16 copy ----------------
__global__ __launch_bounds__(256) void ln_residual_kernel(float* __restrict__ x,
                                                          const float* __restrict__ res,
                                                          const float* __restrict__ g,
                                                          const float* __restrict__ b,
                                                          unsigned short* __restrict__ xb) {
  int row = blockIdx.x, tid = threadIdx.x;
  __shared__ float red[256];
  float* xr = x + (size_t)row * DM;
  const float* rr = res + (size_t)row * DM;
  float v0 = xr[tid] + rr[tid];
  float v1 = xr[tid + 256] + rr[tid + 256];
  red[tid] = v0 + v1;
  __syncthreads();
  if (tid < 128) red[tid] += red[tid + 128];
  __syncthreads();
  if (tid < 64) red[tid] += red[tid + 64];
  __syncthreads();
  float rv = red[tid & 63];
  #pragma unroll
  for (int s = 32; s > 0; s >>= 1) rv += __shfl_down(rv, s);
  float mu = __shfl(rv, 0) * (1.f / DM);
  __syncthreads();  // WAR: red reuse
  float d0 = v0 - mu, d1 = v1 - mu;
  red[tid] = d0 * d0 + d1 * d1;
  __syncthreads();
  if (tid < 128) red[tid] += red[tid + 128];
  __syncthreads();
  if (tid < 64) red[tid] += red[tid + 64];
  __syncthreads();
  rv = red[tid & 63];
  #pragma unroll
  for (int s = 32; s > 0; s >>= 1) rv += __shfl_down(rv, s);
  float rstd = rsqrtf(__shfl(rv, 0) * (1.f / DM) + 1e-5f);
  float o0 = d0 * rstd * g[tid] + b[tid];
  float o1 = d1 * rstd * g[tid + 256] + b[tid + 256];
  xr[tid] = o0;
  xr[tid + 256] = o1;
  xb[(size_t)row * DM + tid] = f2bf(o0);
  xb[(size_t)row * DM + tid + 256] = f2bf(o1);
}

// ---------------- whh i8 pack, (jl,kh)-lane layout ----------------
__global__ void pack_whh_q8_kernel(const float* __restrict__ whh, signed char* __restrict__ whhJ,
                                   float* __restrict__ sws) {
  int row = blockIdx.x;   // 0..1535 = g*512 + j
  int lane = threadIdx.x; // 64
  const float* src = whh + (size_t)row * 512;
  float mx = 0.f;
  for (int k = lane; k < 512; k += 64) mx = fmaxf(mx, fabsf(src[k]));
  for (int off = 32; off > 0; off >>= 1) mx = fmaxf(mx, __shfl_xor(mx, off));
  float inv = (mx > 0.f) ? 127.f / mx : 0.f;
  if (lane == 0) sws[row] = (mx / 127.f) * (8.f / 127.f);
  int g = row >> 9, jj = row & 511;
  int quad = jj >> 7, jl = jj & 127;
  for (int k = lane; k < 512; k += 64) {
    int qv = (int)rintf(src[k] * inv);
    qv = qv < -127 ? -127 : (qv > 127 ? 127 : qv);
    int kh = k >> 6, u = (k >> 4) & 3, m = k & 15;
    whhJ[((size_t)(((quad * 128 + jl) * 8 + kh) * 4 + u) * 3 + g) * 16 + m] = (signed char)qv;
  }
}

// ---------------- Langevin scan: 4 blocks per batch (j-split) ----------------
// R2-proven design (~597us): exchange chain is the ~3.1us/step structural floor.
__global__ __launch_bounds__(1024, 4) void langevin_scan_kernel(
    const float* __restrict__ gi_all, const float* __restrict__ hx0,
    const signed char* __restrict__ whhJ, const float* __restrict__ sws,
    const float* __restrict__ bhh, const float* __restrict__ score_w,
    unsigned short* __restrict__ dgiB, unsigned long long* __restrict__ hqg, int tagBase) {
  int b = blockIdx.x, quad = blockIdx.y;
  int tid = threadIdx.x;
  __shared__ __align__(16) unsigned int hqp[2][160];  // [buf][kh*20 + r], r<16 used
  int jl = tid >> 3, kh = tid & 7;
  int j = quad * 128 + jl;
  bool act = (kh == 0);
  float bhr = 0.f, bhz = 0.f, bhn = 0.f, sw = 0.f, swr = 0.f, swz = 0.f, swn = 0.f, h = 0.f;
  if (act) {
    bhr = bhh[j]; bhz = bhh[512 + j]; bhn = bhh[1024 + j];
    sw = score_w[j] * COF;
    swr = sws[j]; swz = sws[512 + j]; swn = sws[1024 + j];
    h = hx0[(size_t)b * 512 + j];
  }
  if (tid < 128) {
    float4 hv = *(const float4*)&hx0[(size_t)b * 512 + tid * 4];
    float tmp[4] = {hv.x, hv.y, hv.z, hv.w};
    hqp[0][(tid >> 4) * 20 + (tid & 15)] = packq4(tmp);
  }
  const u32x4* wbase = (const u32x4*)whhJ + (size_t)((quad * 128 + jl) * 8 + kh) * 12;
  u32x4 wreg[12];
  #pragma unroll
  for (int i = 0; i < 12; i++) wreg[i] = wbase[i];
  #pragma unroll
  for (int i = 0; i < 12; i++) asm volatile("" : "+v"(wreg[i]));
  // prefetch gi for t=0 and t=1 (distance-2 pipeline)
  float gir = 0.f, giz = 0.f, gin = 0.f, gir1 = 0.f, giz1 = 0.f, gin1 = 0.f;
  if (act) {
    const float* g0 = &gi_all[(size_t)b * TT * 1536];
    gir = g0[j]; giz = g0[512 + j]; gin = g0[1024 + j];
    const float* g1 = g0 + 1536;
    gir1 = g1[j]; giz1 = g1[512 + j]; gin1 = g1[1024 + j];
  }
  __syncthreads();
  for (int t = 0; t < TT; t++) {
    int rb = t & 1;
    int ir = 0, iz = 0, in_ = 0;
    #pragma unroll
    for (int u = 0; u < 4; u++) {
      u32x4 hqv = *(const u32x4*)&hqp[rb][kh * 20 + u * 4];
      ir = sd16(wreg[u * 3 + 0], hqv, ir);
      iz = sd16(wreg[u * 3 + 1], hqv, iz);
      in_ = sd16(wreg[u * 3 + 2], hqv, in_);
    }
    #pragma unroll
    for (int d = 1; d < 8; d <<= 1) {
      ir += __shfl_xor(ir, d);
      iz += __shfl_xor(iz, d);
      in_ += __shfl_xor(in_, d);
    }
    int qv = 0;
    float r = 0.f, z = 0.f, n = 0.f, hnv = 0.f, hj = 0.f;
    if (act) {
      float gr = (float)ir * swr, gz = (float)iz * swz, gn2 = (float)in_ * swn;
      r = 1.f / (1.f + expf(-(gir + gr + bhr)));
      z = 1.f / (1.f + expf(-(giz + gz + bhz)));
      hnv = gn2 + bhn;
      n = tanhf(gin + r * hnv);
      hj = h;
      h = (1.f - z) * n + z * hj;
      int q = (int)rintf(h * 15.875f);
      qv = q < -127 ? -127 : (q > 127 ? 127 : q);
    }
    // gather 4 consecutive j's i8 into owner lanes (tid%32==0) via in-wave shuffles
    int l = tid & 63;
    int q1 = __shfl(qv, (l + 8) & 63);
    int q2 = __shfl(qv, (l + 16) & 63);
    int q3 = __shfl(qv, (l + 24) & 63);
    bool ex = (t + 1 < TT);
    int wb = (t + 1) & 1;
    unsigned tag = (unsigned)(tagBase + t + 1);
    if (ex && (tid & 31) == 0) {
      unsigned word = (unsigned)(qv & 0xff) | ((unsigned)(q1 & 0xff) << 8) |
                      ((unsigned)(q2 & 0xff) << 16) | ((unsigned)(q3 & 0xff) << 24);
      int w = quad * 32 + (tid >> 5);
      hqp[wb][(w >> 4) * 20 + (w & 15)] = word;
      __hip_atomic_store(&hqg[((size_t)wb * BATCH + b) * 128 + w],
                         ((unsigned long long)tag << 32) | (unsigned long long)word,
                         __ATOMIC_RELAXED, __HIP_MEMORY_SCOPE_AGENT);
    }
    // gradient math off the publish->poll chain (pure VALU, overlaps store ack)
    float dg0 = 0.f, dg1 = 0.f, dg2 = 0.f;
    if (act) {
      float dinn = sw * (1.f - z) * (1.f - n * n);
      dg0 = dinn * hnv * r * (1.f - r);
      dg1 = sw * (hj - n) * z * (1.f - z);
      dg2 = dinn;
    }
    if (ex && kh == 1 && jl < 96) {
      int o = jl >> 5;
      int oq = (quad + 1 + o) & 3;
      int w = oq * 32 + (jl & 31);
      unsigned long long* p = &hqg[((size_t)wb * BATCH + b) * 128 + w];
      unsigned long long v = __hip_atomic_load(p, __ATOMIC_RELAXED, __HIP_MEMORY_SCOPE_AGENT);
      while ((unsigned)(v >> 32) != tag) {
        __builtin_amdgcn_s_sleep(1);
        v = __hip_atomic_load(p, __ATOMIC_RELAXED, __HIP_MEMORY_SCOPE_AGENT);
      }
      hqp[wb][(w >> 4) * 20 + (w & 15)] = (unsigned)v;
    }
    // keep the following VMEM ops AFTER the poll so its vmcnt(0) never waits on them
    __builtin_amdgcn_sched_barrier(0);
    // gi prefetch for t+2 (distance 2: fully hidden, off every poll's chain)
    float girP = 0.f, gizP = 0.f, ginP = 0.f;
    if (act && t + 2 < TT) {
      const float* gp = &gi_all[((size_t)b * TT + t + 2) * 1536];
      girP = gp[j]; gizP = gp[512 + j]; ginP = gp[1024 + j];
    }
    // dgi stores drain during barrier + next step's dots
    if (act) {
      size_t drow = ((size_t)b * TT + t) * 1536;
      dgiB[drow + j] = f2bf(dg0);
      dgiB[drow + 512 + j] = f2bf(dg1);
      dgiB[drow + 1024 + j] = f2bf(dg2);
    }
    if (ex) __syncthreads();
    gir = gir1; giz = giz1; gin = gin1;
    gir1 = girP; giz1 = gizP; gin1 = ginP;
  }
}

// fused: sum 4 K-split partials, AXPY (out = xi - alpha*g), denorm, loss partial
__global__ __launch_bounds__(256) void denorm_loss_fused_kernel(
    const float* __restrict__ P, const float* __restrict__ R,
    const float* __restrict__ alphaPtr, const float* __restrict__ stdev,
    const float* __restrict__ means, const float* __restrict__ y,
    float* __restrict__ outn, float* __restrict__ dout, float* __restrict__ loss) {
  int idx = blockIdx.x * 256 + threadIdx.x;
  int tid = threadIdx.x;
  int c = idx & 63;
  int bt = idx >> 6;
  int t = bt % TT, b = bt / TT;
  float al = alphaPtr[0];
  float val = P[idx] + P[OUTN + idx] + P[2 * (size_t)OUTN + idx] + P[3 * (size_t)OUTN + idx];
  float on = R[idx] - al * val;
  outn[idx] = on;
  float od = on * stdev[b * CIN + c] + means[b * CIN + c];
  dout[idx] = od;
  float diff = fabsf(od - y[((size_t)b * 240 + 48 + t) * CIN + c]);
  __shared__ float red[256];
  red[tid] = diff;
  __syncthreads();
  if (tid < 128) red[tid] += red[tid + 128];
  __syncthreads();
  if (tid < 64) red[tid] += red[tid + 64];
  __syncthreads();
  if (tid < 64) {
    float rv = red[tid];
    #pragma unroll
    for (int s = 32; s > 0; s >>= 1) rv += __shfl_down(rv, s);
    if (tid == 0) atomicAdd(loss, rv);
  }
}

// ---------------- host launch ----------------
extern "C" void kernel_launch(void* const* d_in, const int* in_sizes, int n_in, void* d_out,
                              int out_size, void* d_ws, size_t ws_size, hipStream_t stream) {
  const float* x_enc = (const float*)d_in[0];
  const float* batch_y = (const float*)d_in[2];
  const float* y_mark = (const float*)d_in[3];
  const float* hx_init = (const float*)d_in[4];
  const float* conv_w = (const float*)d_in[5];
  const float* tf_w = (const float*)d_in[6];
  const float* Wq = (const float*)d_in[7];
  const float* Wk = (const float*)d_in[8];
  const float* Wv = (const float*)d_in[9];
  const float* Wo = (const float*)d_in[10];
  const float* bq = (const float*)d_in[11];
  const float* bk = (const float*)d_in[12];
  const float* bv = (const float*)d_in[13];
  const float* bo = (const float*)d_in[14];
  const float* ln1_g = (const float*)d_in[15];
  const float* ln1_b = (const float*)d_in[16];
  const float* W1 = (const float*)d_in[17];
  const float* b1 = (const float*)d_in[18];
  const float* W2 = (const float*)d_in[19];
  const float* b2 = (const float*)d_in[20];
  const float* ln2_g = (const float*)d_in[21];
  const float* ln2_b = (const float*)d_in[22];
  const float* pl1_w = (const float*)d_in[23];
  const float* pl1_b = (const float*)d_in[24];
  const float* pl2_w = (const float*)d_in[25];
  const float* pl2_b = (const float*)d_in[26];
  const float* proj_w = (const float*)d_in[27];
  const float* proj_b = (const float*)d_in[28];
  const float* gru_wih = (const float*)d_in[29];
  const float* gru_whh = (const float*)d_in[30];
  const float* gru_bih = (const float*)d_in[31];
  const float* gru_bhh = (const float*)d_in[32];
  const float* score_w = (const float*)d_in[33];
  const float* alpha = (const float*)d_in[34];
  float* dout = (float*)d_out;

  float* W = (float*)d_ws;
  size_t off = 0;
  float* means = W + off;   off += 2048;
  float* stdev = W + off;   off += 2048;
  float* lossacc = W + off; off += 64;
  float* preA = W + off;    off += (size_t)OUTN;
  float* outA = W + off;    off += (size_t)OUTN;
  float* outB = W + off;    off += (size_t)OUTN;
  float* corrupt = W + off; off += (size_t)OUTN;
  float* peT = W + off;     off += (size_t)TT * DM;   // PE table
  float* Wemb = W + off;    off += (size_t)KEMB * DM; // embed GEMM weights (persist)
  float* axp = W + off;     off += (size_t)4 * OUTN;  // K-split AXPY partials
  float* Xp = axp;  // alias: axp dead at embed time (written later by axpy_partial)
  signed char* whhJ = (signed char*)(W + off); off += 786432 / 4;
  float* sws = W + off;     off += 1536;
  unsigned long long* hqg = (unsigned long long*)(W + off); off += 2 * BATCH * 128 * 2;  // 8192 qwords
  float* emb = W + off;     off += (size_t)BATCH * TT * DM;
  float* Kb = W + off;      off += (size_t)BATCH * TT * DM;
  float* gi_all = W + off;  off += (size_t)BATCH * TT * 1536;
  unsigned short* embB = (unsigned short*)(W + off);  off += (size_t)BATCH * TT * DM / 2;
  unsigned short* qkvB = (unsigned short*)(W + off);  off += (size_t)BATCH * TT * 1536 / 2;
  unsigned short* attnOB = (unsigned short*)(W + off); off += (size_t)BATCH * TT * DM / 2;
  unsigned short* FFbB = (unsigned short*)(W + off);  off += (size_t)BATCH * TT * DFF / 2;
  unsigned short* xcatB = (unsigned short*)(W + off); off += (size_t)BATCH * TT * 128 / 2;
  float* bqkv = W + off;    off += 2 * 1536;
  unsigned short* WxProjB = (unsigned short*)(W + off); off += (size_t)128 * 1536 / 2;
  unsigned short* wT = (unsigned short*)(W + off);
  const size_t SQ = (size_t)DM * DM;
  const size_t SFF = (size_t)DM * DFF;
  const size_t LAYER = 4 * SQ + 2 * SFF;
  unsigned short* wihB = wT + 2 * LAYER;
  off += (2 * LAYER + (size_t)1536 * 128) / 2 + 64;
  unsigned short* dgiB = qkvB;  // alias: qkvB dead after attention, reused for dgi

  const int M = BATCH * TT;  // 6144

  zero_loss_kernel<<<1, 64, 0, stream>>>(lossacc);
  zero_hqg_kernel<<<32, 256, 0, stream>>>(hqg);  // clear stale tags (graph-replay safety)
  pe_table_kernel<<<TT, DM, 0, stream>>>(peT);
  build_wemb_kernel<<<(KEMB * DM) / 256, 256, 0, stream>>>(conv_w, tf_w, Wemb);
  stats_kernel<<<BATCH, 64, 0, stream>>>(x_enc, means, stdev);
  pl1_kernel<<<dim3(TT, BATCH), 64, 0, stream>>>(x_enc, means, stdev, pl1_w, pl1_b, preA);
  pack_whh_q8_kernel<<<1536, 64, 0, stream>>>(gru_whh, whhJ, sws);
  pack_wxproj_kernel<<<(128 * 1536) / 256, 256, 0, stream>>>(gru_wih, WxProjB);
  concat_qkv_bias_kernel<<<dim3(6, 2), 256, 0, stream>>>(bq, bk, bv, bqkv);
  for (int l = 0; l < 2; l++) {
    unsigned short* base = wT + (size_t)l * LAYER;
    pack_transpose_bf16_kernel<<<dim3(8, 8), 256, 0, stream>>>(Wq + (size_t)l * SQ, base, DM, DM);
    pack_transpose_bf16_kernel<<<dim3(8, 8), 256, 0, stream>>>(Wk + (size_t)l * SQ, base + SQ, DM, DM);
    pack_transpose_bf16_kernel<<<dim3(8, 8), 256, 0, stream>>>(Wv + (size_t)l * SQ, base + 2 * SQ, DM, DM);
    pack_transpose_bf16_kernel<<<dim3(8, 8), 256, 0, stream>>>(Wo + (size_t)l * SQ, base + 3 * SQ, DM, DM);
    pack_transpose_bf16_kernel<<<dim3(8, 32), 256, 0, stream>>>(W1 + (size_t)l * SFF, base + 4 * SQ, DM, DFF);
    pack_transpose_bf16_kernel<<<dim3(32, 8), 256, 0, stream>>>(W2 + (size_t)l * SFF, base + 4 * SQ + SFF, DFF, DM);
  }
  pack_bf16_kernel<<<(1536 * 128) / 256, 256, 0, stream>>>(gru_wih, wihB, 1536 * 128);

  const float* pre = preA;
  float* outs[2] = {outA, outB};
  for (int s = 0; s < 2; s++) {
    pl2_kernel<<<dim3(TT, BATCH), 64, 0, stream>>>(pre, pl2_w, pl2_b, corrupt, xcatB);
    // embed as GEMM: Xp[6144x208] @ Wemb[208x512] + PE, writes emb f32 + embB bf16
    build_xp_kernel<<<(M * KEMB) / 256, 256, 0, stream>>>(corrupt, y_mark, Xp);
    gemm_kernel<0, 0, 0, 1><<<dim3(DM / 64, M / 64), 256, 0, stream>>>(
        Xp, Wemb, nullptr, emb, nullptr, peT, embB, M, DM, KEMB);
    for (int l = 0; l < 2; l++) {
      unsigned short* base = wT + (size_t)l * LAYER;
      gemm_bf16_kernel<0, 0, 1><<<dim3(1536 / 128, M / 128), 256, 0, stream>>>(
          embB, base, bqkv + l * 1536, nullptr, qkvB, M, 1536, DM);
      attention_mfma_kernel<<<dim3(NH, BATCH, 3), 256, 0, stream>>>(qkvB, attnOB);
      gemm_bf16_kernel<0, 1, 0><<<dim3(DM / 128, M / 128), 256, 0, stream>>>(
          attnOB, base + 3 * SQ, bo + l * DM, Kb, nullptr, M, DM, DM);
      ln_residual_kernel<<<M, 256, 0, stream>>>(emb, Kb, ln1_g + l * DM, ln1_b + l * DM, embB);
      gemm_bf16_kernel<1, 0, 1><<<dim3(DFF / 128, M / 128), 256, 0, stream>>>(
          embB, base + 4 * SQ, b1 + l * DFF, nullptr, FFbB, M, DFF, DM);
      gemm_bf16_kernel<0, 1, 0><<<dim3(DM / 128, M / 128), 256, 0, stream>>>(
          FFbB, base + 4 * SQ + SFF, b2 + l * DM, Kb, nullptr, M, DM, DFF);
      ln_residual_kernel<<<M, 256, 0, stream>>>(emb, Kb, ln2_g + l * DM, ln2_b + l * DM, embB);
    }
    // proj: writes cond bf16 straight into xcatB[:,64:128]
    gemm_kernel<1, 0, 1, 0><<<dim3(CIN / 64, M / 64), 256, 0, stream>>>(
        emb, proj_w, proj_b, nullptr, xcatB, nullptr, nullptr, M, CIN, DM);
    gemm_bf16_kernel<0, 1, 0><<<dim3(1536 / 128, M / 128), 256, 0, stream>>>(
        xcatB, wihB, gru_bih, gi_all, nullptr, M, 1536, 128);
    langevin_scan_kernel<<<dim3(BATCH, 4), 1024, 0, stream>>>(
        gi_all, hx_init + (size_t)s * BATCH * DM, whhJ, sws, gru_bhh, score_w, dgiB, hqg,
        s * TT);
    // out = xi - alpha * dgi @ Wx^T : K-split partials (192 blocks) + fused epilogue
    axpy_partial_kernel<<<dim3(4, M / 128), 256, 0, stream>>>(dgiB, WxProjB, axp, M, 1536);
    denorm_loss_fused_kernel<<<OUTN / 256, 256, 0, stream>>>(
        axp, corrupt, alpha, stdev, means, batch_y, outs[s], dout, lossacc);
    pre = outs[s];
  }
  finalize_kernel<<<1, 1, 0, stream>>>(dout, lossacc);
}

// Round 10
// 2141.514 us; speedup vs baseline: 1.0493x; 1.0493x over previous
//
#include <hip/hip_runtime.h>
#include <math.h>

#define BATCH 32
#define TT    192
#define DM    512
#define CIN   64
#define SEQL  336
#define DFF   2048
#define NH    8
#define COF   0.1f
#define OUTN  (BATCH*TT*CIN)   // 393216
#define KEMB  208              // 192 conv + 4 mark + 12 zero-pad
#define MND   ((size_t)BATCH*TT*DM)  // 6144*512

typedef _Float16 h2_t __attribute__((ext_vector_type(2)));
union H2U { unsigned int u; h2_t h; };

typedef short bf16x8 __attribute__((ext_vector_type(8)));
typedef float f32x4 __attribute__((ext_vector_type(4)));
typedef unsigned int u32x4 __attribute__((ext_vector_type(4)));

__device__ __forceinline__ unsigned short f2bf(float v) {
  union { float f; unsigned int u; } a; a.f = v;
  unsigned int r = (a.u + 0x7fffu + ((a.u >> 16) & 1u)) >> 16;  // RNE
  return (unsigned short)r;
}

// async global->LDS 16B: lane l of the wave writes lds_base + l*16
__device__ __forceinline__ void gload16(const unsigned short* g, unsigned short* l) {
  __builtin_amdgcn_global_load_lds(
      (const __attribute__((address_space(1))) void*)g,
      (__attribute__((address_space(3))) void*)l, 16, 0, 0);
}

// signed 4x i8 dot product with i32 accumulate
__device__ __forceinline__ int sd4(unsigned int a, unsigned int b, int c) {
#if __has_builtin(__builtin_amdgcn_sdot4)
  return __builtin_amdgcn_sdot4((int)a, (int)b, c, false);
#else
  c += (int)(signed char)(a & 0xff) * (int)(signed char)(b & 0xff);
  c += (int)(signed char)((a >> 8) & 0xff) * (int)(signed char)((b >> 8) & 0xff);
  c += (int)(signed char)((a >> 16) & 0xff) * (int)(signed char)((b >> 16) & 0xff);
  c += (int)(signed char)(a >> 24) * (int)(signed char)(b >> 24);
  return c;
#endif
}

__device__ __forceinline__ int sd16(u32x4 w, u32x4 h, int acc) {
  acc = sd4(w[0], h[0], acc); acc = sd4(w[1], h[1], acc);
  acc = sd4(w[2], h[2], acc); acc = sd4(w[3], h[3], acc);
  return acc;
}

// quantize 4 floats (scale 127/8) into one packed i8x4 word
__device__ __forceinline__ unsigned int packq4(const float* hp) {
  int a = (int)rintf(hp[0] * 15.875f); a = a < -127 ? -127 : (a > 127 ? 127 : a);
  int b = (int)rintf(hp[1] * 15.875f); b = b < -127 ? -127 : (b > 127 ? 127 : b);
  int c = (int)rintf(hp[2] * 15.875f); c = c < -127 ? -127 : (c > 127 ? 127 : c);
  int d = (int)rintf(hp[3] * 15.875f); d = d < -127 ? -127 : (d > 127 ? 127 : d);
  return (unsigned int)((a & 0xff) | ((b & 0xff) << 8) | ((c & 0xff) << 16) |
                        ((d & 0xff) << 24));
}

// ---------------- small utility kernels ----------------

__global__ void zero_loss_kernel(float* loss) {
  if (threadIdx.x == 0) loss[0] = 0.f;
}

__global__ void zero_hqg_kernel(unsigned long long* p) {
  p[blockIdx.x * 256 + threadIdx.x] = 0ull;  // 32 blocks x 256 = 8192 qwords
}

__global__ void finalize_kernel(float* dout, const float* loss) {
  dout[OUTN] = loss[0] * (1.f / (float)OUTN);
}

// positional-encoding table, batch-independent: same formula as original (bit-identical)
__global__ void pe_table_kernel(float* __restrict__ peT) {
  int t = blockIdx.x, d = threadIdx.x;  // 192 x 512
  int i2 = (d >> 1) * 2;
  float freq = expf((float)i2 * (-9.210340371976184f / (float)DM));
  float ang = (float)t * freq;
  peT[(size_t)t * DM + d] = (d & 1) ? cosf(ang) : sinf(ang);
}

// Wemb[208][512]: rows 0..191 = conv_w, rows 192..195 = tf_w, rows 196..207 = 0
__global__ void build_wemb_kernel(const float* __restrict__ conv_w,
                                  const float* __restrict__ tf_w, float* __restrict__ Wemb) {
  int idx = blockIdx.x * 256 + threadIdx.x;  // 208*512
  int n = idx % DM, k = idx / DM;
  float v = 0.f;
  if (k < 192) v = conv_w[(size_t)k * DM + n];
  else if (k < 196) v = tf_w[(size_t)(k - 192) * DM + n];
  Wemb[idx] = v;
}

// Xp[row=b*TT+t][208] = [corrupt[b][t-1] | corrupt[b][t] | corrupt[b][t+1] | mark | 0]
__global__ void build_xp_kernel(const float* __restrict__ corrupt,
                                const float* __restrict__ ymark, float* __restrict__ Xp) {
  int idx = blockIdx.x * 256 + threadIdx.x;  // 6144*208
  int col = idx % KEMB, row = idx / KEMB;
  int b = row / TT, t = row % TT;
  float v;
  if (col < 64) {
    int tm = (t + TT - 1) % TT;
    v = corrupt[((size_t)b * TT + tm) * CIN + col];
  } else if (col < 128) {
    v = corrupt[((size_t)b * TT + t) * CIN + (col - 64)];
  } else if (col < 192) {
    int tp = (t + 1) % TT;
    v = corrupt[((size_t)b * TT + tp) * CIN + (col - 128)];
  } else if (col < 196) {
    v = ymark[((size_t)b * 240 + 48 + t) * 4 + (col - 192)];
  } else {
    v = 0.f;
  }
  Xp[idx] = v;
}

__global__ void stats_kernel(const float* __restrict__ x, float* __restrict__ means,
                             float* __restrict__ stdev) {
  int b = blockIdx.x, c = threadIdx.x;  // 64 threads
  const float* xb = x + (size_t)b * SEQL * CIN + c;
  float s = 0.f;
  for (int t = 0; t < SEQL; t++) s += xb[t * CIN];
  float mu = s * (1.f / SEQL);
  float s2 = 0.f;
  for (int t = 0; t < SEQL; t++) { float d = xb[t * CIN] - mu; s2 += d * d; }
  means[b * CIN + c] = mu;
  stdev[b * CIN + c] = sqrtf(s2 * (1.f / SEQL) + 1e-5f);
}

__global__ void pl1_kernel(const float* __restrict__ x, const float* __restrict__ means,
                           const float* __restrict__ stdev, const float* __restrict__ w,
                           const float* __restrict__ bias, float* __restrict__ pre) {
  int p = blockIdx.x, b = blockIdx.y, c = threadIdx.x;  // 64 threads
  float mu = means[b * CIN + c];
  float inv = 1.f / stdev[b * CIN + c];
  const float* xb = x + (size_t)b * SEQL * CIN + c;
  const float* wp = w + p * SEQL;
  float acc = 0.f;
  for (int t = 0; t < SEQL; t++) acc += (xb[t * CIN] - mu) * wp[t];
  pre[((size_t)b * TT + p) * CIN + c] = acc * inv + bias[p];
}

// pl2: corrupt f32 + bf16 copy into xcatB[:,0:64]
__global__ void pl2_kernel(const float* __restrict__ pre, const float* __restrict__ w,
                           const float* __restrict__ bias, float* __restrict__ out,
                           unsigned short* __restrict__ xc) {
  int q = blockIdx.x, b = blockIdx.y, c = threadIdx.x;  // 64 threads
  const float* pb = pre + (size_t)b * TT * CIN + c;
  const float* wq = w + q * TT;
  float acc = 0.f;
  for (int p = 0; p < TT; p++) acc += pb[p * CIN] * wq[p];
  float val = acc + bias[q];
  size_t r = (size_t)b * TT + q;
  out[r * CIN + c] = val;
  xc[r * 128 + c] = f2bf(val);
}

// ---------------- fp32 GEMM ----------------
// XC=1: write bf16 into xcatB[:,64:128] (proj). EMB=1: add peT[t][col], write
// emb f32 + embB bf16 (embed conv-as-GEMM).
template <int TB, int RELU, int XC, int EMB>
__global__ __launch_bounds__(256) void gemm_kernel(const float* __restrict__ A,
                                                   const float* __restrict__ B,
                                                   const float* __restrict__ bias,
                                                   float* __restrict__ C,
                                                   unsigned short* __restrict__ Cx,
                                                   const float* __restrict__ PE,
                                                   unsigned short* __restrict__ Cb2,
                                                   int M, int N, int K) {
  __shared__ float As[16][68];
  __shared__ float Bs[16][68];
  int tid = threadIdx.x;
  int bn = blockIdx.x * 64, bm = blockIdx.y * 64;
  int tx = tid & 15, ty = tid >> 4;
  int row0 = ty * 4, col0 = tx * 4;
  float acc[4][4] = {};
  for (int k0 = 0; k0 < K; k0 += 16) {
    {
      int m = tid >> 2, kq = (tid & 3) << 2;
      float4 av = *(const float4*)&A[(size_t)(bm + m) * K + k0 + kq];
      As[kq + 0][m] = av.x; As[kq + 1][m] = av.y; As[kq + 2][m] = av.z; As[kq + 3][m] = av.w;
    }
    if (TB) {
      int n = tid >> 2, kq = (tid & 3) << 2;
      float4 bv = *(const float4*)&B[(size_t)(bn + n) * K + k0 + kq];
      Bs[kq + 0][n] = bv.x; Bs[kq + 1][n] = bv.y; Bs[kq + 2][n] = bv.z; Bs[kq + 3][n] = bv.w;
    } else {
      int kk = tid >> 4, nq = (tid & 15) << 2;
      float4 bv = *(const float4*)&B[(size_t)(k0 + kk) * N + bn + nq];
      *(float4*)&Bs[kk][nq] = bv;
    }
    __syncthreads();
    #pragma unroll
    for (int k = 0; k < 16; k++) {
      float4 a4 = *(const float4*)&As[k][row0];
      float4 b4 = *(const float4*)&Bs[k][col0];
      float a[4] = {a4.x, a4.y, a4.z, a4.w};
      float bb[4] = {b4.x, b4.y, b4.z, b4.w};
      #pragma unroll
      for (int i = 0; i < 4; i++)
        #pragma unroll
        for (int j = 0; j < 4; j++) acc[i][j] += a[i] * bb[j];
    }
    __syncthreads();
  }
  float bv[4] = {0.f, 0.f, 0.f, 0.f};
  if (bias) *(float4*)bv = *(const float4*)&bias[bn + col0];
  #pragma unroll
  for (int i = 0; i < 4; i++) {
    int row = bm + row0 + i;
    float pe[4] = {0.f, 0.f, 0.f, 0.f};
    if (EMB) {
      int t = row % TT;
      *(float4*)pe = *(const float4*)&PE[(size_t)t * DM + bn + col0];
    }
    float ov[4];
    #pragma unroll
    for (int j = 0; j < 4; j++) {
      float v = acc[i][j] + bv[j];
      if (EMB) v += pe[j];
      if (RELU) v = fmaxf(v, 0.f);
      ov[j] = v;
    }
    if (XC) {
      unsigned short xv[4];
      #pragma unroll
      for (int j = 0; j < 4; j++) xv[j] = f2bf(ov[j]);
      *(uint2*)&Cx[(size_t)row * 128 + 64 + bn + col0] = *(uint2*)xv;
    } else {
      *(float4*)&C[(size_t)row * N + bn + col0] = *(float4*)ov;
      if (EMB) {
        unsigned short xv[4];
        #pragma unroll
        for (int j = 0; j < 4; j++) xv[j] = f2bf(ov[j]);
        *(uint2*)&Cb2[(size_t)row * N + bn + col0] = *(uint2*)xv;
      }
    }
  }
}

// ---------------- bf16 MFMA GEMM (bf16 A, bf16 Bt [N][K]) ----------------
// PART=1: K-split over blockIdx.z (2 halves); writes f32 partials to
// C[z*M*N + ...], NO bias (consumer sums partials + bias). Fixes the 192-block
// (0.75/CU) serial-K bottleneck of the N=512 GEMMs (O-proj K=512, FF2 K=2048).
template <int RELU, int WF32, int WBF16, int PART>
__global__ __launch_bounds__(256) void gemm_bf16_kernel(
    const unsigned short* __restrict__ A, const unsigned short* __restrict__ Bt,
    const float* __restrict__ bias, float* __restrict__ C, unsigned short* __restrict__ Cb,
    int M, int N, int K) {
  __shared__ __align__(16) unsigned short As[128 * 32];
  __shared__ __align__(16) unsigned short Bs[128 * 32];
  int tid = threadIdx.x;
  int bm = blockIdx.y * 128, bn = blockIdx.x * 128;
  int wave = tid >> 6, lane = tid & 63;
  int wm = (wave >> 1) * 64, wn = (wave & 1) * 64;
  int r15 = lane & 15, q = lane >> 4;
  f32x4 acc[4][4] = {};
  int srow = wave * 32 + (lane >> 2);
  int scol = (lane & 3) * 8;
  int kbeg = 0, kend = K;
  if (PART) {
    int kq = blockIdx.z;
    kbeg = kq * (K >> 1);
    kend = (kq + 1) * (K >> 1);
  }
  for (int k0 = kbeg; k0 < kend; k0 += 32) {
    gload16(&A[(size_t)(bm + srow) * K + k0 + scol], &As[(wave * 32) * 32]);
    gload16(&A[(size_t)(bm + srow + 16) * K + k0 + scol], &As[(wave * 32 + 16) * 32]);
    gload16(&Bt[(size_t)(bn + srow) * K + k0 + scol], &Bs[(wave * 32) * 32]);
    gload16(&Bt[(size_t)(bn + srow + 16) * K + k0 + scol], &Bs[(wave * 32 + 16) * 32]);
    __syncthreads();
    bf16x8 af[4], bfr[4];
    #pragma unroll
    for (int mi = 0; mi < 4; mi++)
      af[mi] = *(const bf16x8*)&As[(wm + mi * 16 + r15) * 32 + q * 8];
    #pragma unroll
    for (int ni = 0; ni < 4; ni++)
      bfr[ni] = *(const bf16x8*)&Bs[(wn + ni * 16 + r15) * 32 + q * 8];
    #pragma unroll
    for (int mi = 0; mi < 4; mi++)
      #pragma unroll
      for (int ni = 0; ni < 4; ni++)
        acc[mi][ni] =
            __builtin_amdgcn_mfma_f32_16x16x32_bf16(af[mi], bfr[ni], acc[mi][ni], 0, 0, 0);
    __syncthreads();
  }
  size_t pofs = PART ? (size_t)blockIdx.z * ((size_t)M * N) : 0;
  #pragma unroll
  for (int mi = 0; mi < 4; mi++) {
    #pragma unroll
    for (int ni = 0; ni < 4; ni++) {
      int col = bn + wn + ni * 16 + r15;
      float bv = (!PART && bias) ? bias[col] : 0.f;
      #pragma unroll
      for (int v = 0; v < 4; v++) {
        int row = bm + wm + mi * 16 + q * 4 + v;
        float val = acc[mi][ni][v] + bv;
        if (RELU) val = fmaxf(val, 0.f);
        if (PART) C[pofs + (size_t)row * N + col] = val;
        if (WF32) C[(size_t)row * N + col] = val;
        if (WBF16) Cb[(size_t)row * N + col] = f2bf(val);
      }
    }
  }
}

// K-split partial GEMM for the AXPY path: grid (4, M/128)
__global__ __launch_bounds__(256) void axpy_partial_kernel(
    const unsigned short* __restrict__ A, const unsigned short* __restrict__ Bt,
    float* __restrict__ P, int M, int K) {
  __shared__ __align__(16) unsigned short As[128 * 32];
  __shared__ __align__(16) unsigned short Bs[128 * 32];
  int tid = threadIdx.x;
  int kq = blockIdx.x;
  int bm = blockIdx.y * 128;
  int wave = tid >> 6, lane = tid & 63;
  int wm = (wave >> 1) * 64, wn = (wave & 1) * 64;
  int r15 = lane & 15, q = lane >> 4;
  f32x4 acc[4][4] = {};
  int srow = wave * 32 + (lane >> 2);
  int scol = (lane & 3) * 8;
  int kbeg = kq * (K >> 2), kend = (kq + 1) * (K >> 2);
  for (int k0 = kbeg; k0 < kend; k0 += 32) {
    gload16(&A[(size_t)(bm + srow) * K + k0 + scol], &As[(wave * 32) * 32]);
    gload16(&A[(size_t)(bm + srow + 16) * K + k0 + scol], &As[(wave * 32 + 16) * 32]);
    gload16(&Bt[(size_t)srow * K + k0 + scol], &Bs[(wave * 32) * 32]);
    gload16(&Bt[(size_t)(srow + 16) * K + k0 + scol], &Bs[(wave * 32 + 16) * 32]);
    __syncthreads();
    bf16x8 af[4], bfr[4];
    #pragma unroll
    for (int mi = 0; mi < 4; mi++)
      af[mi] = *(const bf16x8*)&As[(wm + mi * 16 + r15) * 32 + q * 8];
    #pragma unroll
    for (int ni = 0; ni < 4; ni++)
      bfr[ni] = *(const bf16x8*)&Bs[(wn + ni * 16 + r15) * 32 + q * 8];
    #pragma unroll
    for (int mi = 0; mi < 4; mi++)
      #pragma unroll
      for (int ni = 0; ni < 4; ni++)
        acc[mi][ni] =
            __builtin_amdgcn_mfma_f32_16x16x32_bf16(af[mi], bfr[ni], acc[mi][ni], 0, 0, 0);
    __syncthreads();
  }
  #pragma unroll
  for (int mi = 0; mi < 4; mi++) {
    #pragma unroll
    for (int ni = 0; ni < 4; ni++) {
      int col = wn + ni * 16 + r15;
      if (col < 64) {
        #pragma unroll
        for (int v = 0; v < 4; v++) {
          int row = bm + wm + mi * 16 + q * 4 + v;
          P[(size_t)kq * OUTN + (size_t)row * 64 + col] = acc[mi][ni][v];
        }
      }
    }
  }
}

// tiled transpose-pack: dst[n*K + k] = bf16(src[k*N + n]); coalesced both sides
__global__ __launch_bounds__(256) void pack_transpose_bf16_kernel(
    const float* __restrict__ src, unsigned short* __restrict__ dst, int K, int N) {
  __shared__ unsigned short tile[64][65];
  int kb = blockIdx.x * 64, nb = blockIdx.y * 64;
  int tid = threadIdx.x;
  int tn = tid & 63, tk = tid >> 6;  // 4 rows per pass
  #pragma unroll
  for (int i = 0; i < 16; i++) {
    int k = tk + i * 4;
    tile[k][tn] = f2bf(src[(size_t)(kb + k) * N + nb + tn]);
  }
  __syncthreads();
  int tk2 = tid & 63, tn2 = tid >> 6;
  #pragma unroll
  for (int i = 0; i < 16; i++) {
    int n = tn2 + i * 4;
    dst[(size_t)(nb + n) * K + kb + tk2] = tile[tk2][n];
  }
}

__global__ void pack_bf16_kernel(const float* __restrict__ src, unsigned short* __restrict__ dst,
                                 int n) {
  int idx = blockIdx.x * 256 + threadIdx.x;
  if (idx < n) dst[idx] = f2bf(src[idx]);
}

// WxProjB[n][k] (n<128, k<1536) = n<64 ? bf16(wih[k*128 + n]) : 0
__global__ void pack_wxproj_kernel(const float* __restrict__ wih,
                                   unsigned short* __restrict__ dst) {
  int idx = blockIdx.x * 256 + threadIdx.x;  // 128*1536
  int k = idx % 1536, n = idx / 1536;
  float v = (n < 64) ? wih[(size_t)k * 128 + n] : 0.f;
  dst[idx] = f2bf(v);
}

__global__ void concat_qkv_bias_kernel(const float* __restrict__ bq, const float* __restrict__ bk,
                                       const float* __restrict__ bv, float* __restrict__ dst) {
  int l = blockIdx.y;
  int i = blockIdx.x * 256 + threadIdx.x;  // < 1536
  float v = (i < 512) ? bq[l * 512 + i]
                      : ((i < 1024) ? bk[l * 512 + i - 512] : bv[l * 512 + i - 1024]);
  dst[l * 1536 + i] = v;
}

// ---------------- MFMA attention: one block per (h,b) — R8-proven form ----------------
__global__ __launch_bounds__(256) void attention_mfma_kernel(
    const unsigned short* __restrict__ qkv, unsigned short* __restrict__ attnO) {
  __shared__ __align__(16) unsigned short Ks[192 * 72];
  __shared__ __align__(16) unsigned short Vt[64 * 200];
  __shared__ __align__(16) float Ps[4][16 * 36];
  int h = blockIdx.x, b = blockIdx.y;
  int tid = threadIdx.x, wave = tid >> 6, lane = tid & 63;
  int m = lane & 15, q = lane >> 4;
  const unsigned short* Qg = qkv + (size_t)b * TT * 1536 + h * 64;
  const unsigned short* Kg = Qg + 512;
  const unsigned short* Vg = Qg + 1024;
  for (int idx = tid; idx < 192 * 8; idx += 256) {
    int s = idx >> 3, ch = (idx & 7) * 8;
    *(uint4*)&Ks[s * 72 + ch] = *(const uint4*)&Kg[(size_t)s * 1536 + ch];
  }
  for (int idx = tid; idx < 96 * 8; idx += 256) {
    int sp = idx >> 3, co = (idx & 7) * 8;
    uint4 v0 = *(const uint4*)&Vg[(size_t)(2 * sp) * 1536 + co];
    uint4 v1 = *(const uint4*)&Vg[(size_t)(2 * sp + 1) * 1536 + co];
    const unsigned short* e0 = (const unsigned short*)&v0;
    const unsigned short* e1 = (const unsigned short*)&v1;
    unsigned int* vtw = (unsigned int*)Vt;
    #pragma unroll
    for (int u = 0; u < 8; u++)
      vtw[(co + u) * 100 + sp] = (unsigned int)e0[u] | ((unsigned int)e1[u] << 16);
  }
  __syncthreads();
  float* ps = Ps[wave];
  for (int tile = wave; tile < 12; tile += 4) {
    int t0 = tile * 16;
    bf16x8 qf0 = *(const bf16x8*)&Qg[(size_t)(t0 + m) * 1536 + q * 8];
    bf16x8 qf1 = *(const bf16x8*)&Qg[(size_t)(t0 + m) * 1536 + 32 + q * 8];
    f32x4 S[12];
    #pragma unroll
    for (int nt = 0; nt < 12; nt++) {
      bf16x8 kf0 = *(const bf16x8*)&Ks[(nt * 16 + m) * 72 + q * 8];
      bf16x8 kf1 = *(const bf16x8*)&Ks[(nt * 16 + m) * 72 + 32 + q * 8];
      f32x4 a = {0.f, 0.f, 0.f, 0.f};
      a = __builtin_amdgcn_mfma_f32_16x16x32_bf16(qf0, kf0, a, 0, 0, 0);
      a = __builtin_amdgcn_mfma_f32_16x16x32_bf16(qf1, kf1, a, 0, 0, 0);
      S[nt] = a;
    }
    float mx[4] = {-1e30f, -1e30f, -1e30f, -1e30f};
    #pragma unroll
    for (int nt = 0; nt < 12; nt++)
      #pragma unroll
      for (int v = 0; v < 4; v++) {
        S[nt][v] *= 0.125f;
        mx[v] = fmaxf(mx[v], S[nt][v]);
      }
    #pragma unroll
    for (int d = 1; d < 16; d <<= 1) {
      #pragma unroll
      for (int v = 0; v < 4; v++) mx[v] = fmaxf(mx[v], __shfl_xor(mx[v], d));
    }
    float sm[4] = {0.f, 0.f, 0.f, 0.f};
    #pragma unroll
    for (int nt = 0; nt < 12; nt++)
      #pragma unroll
      for (int v = 0; v < 4; v++) {
        float e = __expf(S[nt][v] - mx[v]);
        S[nt][v] = e;
        sm[v] += e;
      }
    #pragma unroll
    for (int d = 1; d < 16; d <<= 1) {
      #pragma unroll
      for (int v = 0; v < 4; v++) sm[v] += __shfl_xor(sm[v], d);
    }
    float inv[4];
    #pragma unroll
    for (int v = 0; v < 4; v++) inv[v] = 1.f / sm[v];
    f32x4 o[4] = {};
    for (int kc = 0; kc < 6; kc++) {
      asm volatile("s_waitcnt lgkmcnt(0)" ::: "memory");
      #pragma unroll
      for (int half = 0; half < 2; half++) {
        int nt = 2 * kc + half;
        #pragma unroll
        for (int v = 0; v < 4; v++) ps[(q * 4 + v) * 36 + half * 16 + m] = S[nt][v];
      }
      asm volatile("s_waitcnt lgkmcnt(0)" ::: "memory");
      float4 p0 = *(const float4*)&ps[m * 36 + q * 8];
      float4 p1 = *(const float4*)&ps[m * 36 + q * 8 + 4];
      unsigned short tmp[8];
      tmp[0] = f2bf(p0.x); tmp[1] = f2bf(p0.y); tmp[2] = f2bf(p0.z); tmp[3] = f2bf(p0.w);
      tmp[4] = f2bf(p1.x); tmp[5] = f2bf(p1.y); tmp[6] = f2bf(p1.z); tmp[7] = f2bf(p1.w);
      bf16x8 pf = *(bf16x8*)tmp;
      #pragma unroll
      for (int nt2 = 0; nt2 < 4; nt2++) {
        bf16x8 vf = *(const bf16x8*)&Vt[(nt2 * 16 + m) * 200 + kc * 32 + q * 8];
        o[nt2] = __builtin_amdgcn_mfma_f32_16x16x32_bf16(pf, vf, o[nt2], 0, 0, 0);
      }
    }
    #pragma unroll
    for (int nt2 = 0; nt2 < 4; nt2++)
      #pragma unroll
      for (int v = 0; v < 4; v++) {
        size_t row = (size_t)b * TT + t0 + q * 4 + v;
        attnO[row * 512 + h * 64 + nt2 * 16 + m] = f2bf(o[nt2][v] * inv[v]);
      }
  }
}

// ---------------- layernorm with residual (K-split partials), in-place on x ----------------
// res = P[0] + P[MND] + bias (sums the 2 K-split GEMM partials + output bias)
__global__ __launch_bounds__(256) void ln_residual_ks_kernel(float* __restrict__ x,
                                                             const float* __restrict__ P,
                                                             const float* __restrict__ bias,
                                                             const float* __restrict__ g,
                                                             const float* __restrict__ b,
                                                             unsigned short* __restrict__ xb) {
  int row = blockIdx.x, tid = threadIdx.x;
  __shared__ float red[256];
  float* xr = x + (size_t)row * DM;
  const float* p0 = P + (size_t)row * DM;
  const float* p1 = p0 + MND;
  float r0 = p0[tid] + p1[tid] + bias[tid];
  float r1 = p0[tid + 256] + p1[tid + 256] + bias[tid + 256];
  float v0 = xr[tid] + r0;
  float v1 = xr[tid + 256] + r1;
  red[tid] = v0 + v1;
  __syncthreads();
  if (tid < 128) red[tid] += red[tid + 128];
  __syncthreads();
  if (tid < 64) red[tid] += red[tid + 64];
  __syncthreads();
  float rv = red[tid & 63];
  #pragma unroll
  for (int s = 32; s > 0; s >>= 1) rv += __shfl_down(rv, s);
  float mu = __shfl(rv, 0) * (1.f / DM);
  __syncthreads();  // WAR: red reuse
  float d0 = v0 - mu, d1 = v1 - mu;
  red[tid] = d0 * d0 + d1 * d1;
  __syncthreads();
  if (tid < 128) red[tid] += red[tid + 128];
  __syncthreads();
  if (tid < 64) red[tid] += red[tid + 64];
  __syncthreads();
  rv = red[tid & 63];
  #pragma unroll
  for (int s = 32; s > 0; s >>= 1) rv += __shfl_down(rv, s);
  float rstd = rsqrtf(__shfl(rv, 0) * (1.f / DM) + 1e-5f);
  float o0 = d0 * rstd * g[tid] + b[tid];
  float o1 = d1 * rstd * g[tid + 256] + b[tid + 256];
  xr[tid] = o0;
  xr[tid + 256] = o1;
  xb[(size_t)row * DM + tid] = f2bf(o0);
  xb[(size_t)row * DM + tid + 256] = f2bf(o1);
}

// ---------------- whh i8 pack, (jl,kh)-lane layout ----------------
__global__ void pack_whh_q8_kernel(const float* __restrict__ whh, signed char* __restrict__ whhJ,
                                   float* __restrict__ sws) {
  int row = blockIdx.x;   // 0..1535 = g*512 + j
  int lane = threadIdx.x; // 64
  const float* src = whh + (size_t)row * 512;
  float mx = 0.f;
  for (int k = lane; k < 512; k += 64) mx = fmaxf(mx, fabsf(src[k]));
  for (int off = 32; off > 0; off >>= 1) mx = fmaxf(mx, __shfl_xor(mx, off));
  float inv = (mx > 0.f) ? 127.f / mx : 0.f;
  if (lane == 0) sws[row] = (mx / 127.f) * (8.f / 127.f);
  int g = row >> 9, jj = row & 511;
  int quad = jj >> 7, jl = jj & 127;
  for (int k = lane; k < 512; k += 64) {
    int qv = (int)rintf(src[k] * inv);
    qv = qv < -127 ? -127 : (qv > 127 ? 127 : qv);
    int kh = k >> 6, u = (k >> 4) & 3, m = k & 15;
    whhJ[((size_t)(((quad * 128 + jl) * 8 + kh) * 4 + u) * 3 + g) * 16 + m] = (signed char)qv;
  }
}

// ---------------- Langevin scan: 4 blocks per batch (j-split) ----------------
// R2-proven design (~597us): exchange chain is the ~3.1us/step structural floor.
__global__ __launch_bounds__(1024, 4) void langevin_scan_kernel(
    const float* __restrict__ gi_all, const float* __restrict__ hx0,
    const signed char* __restrict__ whhJ, const float* __restrict__ sws,
    const float* __restrict__ bhh, const float* __restrict__ score_w,
    unsigned short* __restrict__ dgiB, unsigned long long* __restrict__ hqg, int tagBase) {
  int b = blockIdx.x, quad = blockIdx.y;
  int tid = threadIdx.x;
  __shared__ __align__(16) unsigned int hqp[2][160];  // [buf][kh*20 + r], r<16 used
  int jl = tid >> 3, kh = tid & 7;
  int j = quad * 128 + jl;
  bool act = (kh == 0);
  float bhr = 0.f, bhz = 0.f, bhn = 0.f, sw = 0.f, swr = 0.f, swz = 0.f, swn = 0.f, h = 0.f;
  if (act) {
    bhr = bhh[j]; bhz = bhh[512 + j]; bhn = bhh[1024 + j];
    sw = score_w[j] * COF;
    swr = sws[j]; swz = sws[512 + j]; swn = sws[1024 + j];
    h = hx0[(size_t)b * 512 + j];
  }
  if (tid < 128) {
    float4 hv = *(const float4*)&hx0[(size_t)b * 512 + tid * 4];
    float tmp[4] = {hv.x, hv.y, hv.z, hv.w};
    hqp[0][(tid >> 4) * 20 + (tid & 15)] = packq4(tmp);
  }
  const u32x4* wbase = (const u32x4*)whhJ + (size_t)((quad * 128 + jl) * 8 + kh) * 12;
  u32x4 wreg[12];
  #pragma unroll
  for (int i = 0; i < 12; i++) wreg[i] = wbase[i];
  #pragma unroll
  for (int i = 0; i < 12; i++) asm volatile("" : "+v"(wreg[i]));
  // prefetch gi for t=0 and t=1 (distance-2 pipeline)
  float gir = 0.f, giz = 0.f, gin = 0.f, gir1 = 0.f, giz1 = 0.f, gin1 = 0.f;
  if (act) {
    const float* g0 = &gi_all[(size_t)b * TT * 1536];
    gir = g0[j]; giz = g0[512 + j]; gin = g0[1024 + j];
    const float* g1 = g0 + 1536;
    gir1 = g1[j]; giz1 = g1[512 + j]; gin1 = g1[1024 + j];
  }
  __syncthreads();
  for (int t = 0; t < TT; t++) {
    int rb = t & 1;
    int ir = 0, iz = 0, in_ = 0;
    #pragma unroll
    for (int u = 0; u < 4; u++) {
      u32x4 hqv = *(const u32x4*)&hqp[rb][kh * 20 + u * 4];
      ir = sd16(wreg[u * 3 + 0], hqv, ir);
      iz = sd16(wreg[u * 3 + 1], hqv, iz);
      in_ = sd16(wreg[u * 3 + 2], hqv, in_);
    }
    #pragma unroll
    for (int d = 1; d < 8; d <<= 1) {
      ir += __shfl_xor(ir, d);
      iz += __shfl_xor(iz, d);
      in_ += __shfl_xor(in_, d);
    }
    int qv = 0;
    float r = 0.f, z = 0.f, n = 0.f, hnv = 0.f, hj = 0.f;
    if (act) {
      float gr = (float)ir * swr, gz = (float)iz * swz, gn2 = (float)in_ * swn;
      r = 1.f / (1.f + expf(-(gir + gr + bhr)));
      z = 1.f / (1.f + expf(-(giz + gz + bhz)));
      hnv = gn2 + bhn;
      n = tanhf(gin + r * hnv);
      hj = h;
      h = (1.f - z) * n + z * hj;
      int q = (int)rintf(h * 15.875f);
      qv = q < -127 ? -127 : (q > 127 ? 127 : q);
    }
    // gather 4 consecutive j's i8 into owner lanes (tid%32==0) via in-wave shuffles
    int l = tid & 63;
    int q1 = __shfl(qv, (l + 8) & 63);
    int q2 = __shfl(qv, (l + 16) & 63);
    int q3 = __shfl(qv, (l + 24) & 63);
    bool ex = (t + 1 < TT);
    int wb = (t + 1) & 1;
    unsigned tag = (unsigned)(tagBase + t + 1);
    if (ex && (tid & 31) == 0) {
      unsigned word = (unsigned)(qv & 0xff) | ((unsigned)(q1 & 0xff) << 8) |
                      ((unsigned)(q2 & 0xff) << 16) | ((unsigned)(q3 & 0xff) << 24);
      int w = quad * 32 + (tid >> 5);
      hqp[wb][(w >> 4) * 20 + (w & 15)] = word;
      __hip_atomic_store(&hqg[((size_t)wb * BATCH + b) * 128 + w],
                         ((unsigned long long)tag << 32) | (unsigned long long)word,
                         __ATOMIC_RELAXED, __HIP_MEMORY_SCOPE_AGENT);
    }
    // gradient math off the publish->poll chain (pure VALU, overlaps store ack)
    float dg0 = 0.f, dg1 = 0.f, dg2 = 0.f;
    if (act) {
      float dinn = sw * (1.f - z) * (1.f - n * n);
      dg0 = dinn * hnv * r * (1.f - r);
      dg1 = sw * (hj - n) * z * (1.f - z);
      dg2 = dinn;
    }
    if (ex && kh == 1 && jl < 96) {
      int o = jl >> 5;
      int oq = (quad + 1 + o) & 3;
      int w = oq * 32 + (jl & 31);
      unsigned long long* p = &hqg[((size_t)wb * BATCH + b) * 128 + w];
      unsigned long long v = __hip_atomic_load(p, __ATOMIC_RELAXED, __HIP_MEMORY_SCOPE_AGENT);
      while ((unsigned)(v >> 32) != tag) {
        __builtin_amdgcn_s_sleep(1);
        v = __hip_atomic_load(p, __ATOMIC_RELAXED, __HIP_MEMORY_SCOPE_AGENT);
      }
      hqp[wb][(w >> 4) * 20 + (w & 15)] = (unsigned)v;
    }
    // keep the following VMEM ops AFTER the poll so its vmcnt(0) never waits on them
    __builtin_amdgcn_sched_barrier(0);
    // gi prefetch for t+2 (distance 2: fully hidden, off every poll's chain)
    float girP = 0.f, gizP = 0.f, ginP = 0.f;
    if (act && t + 2 < TT) {
      const float* gp = &gi_all[((size_t)b * TT + t + 2) * 1536];
      girP = gp[j]; gizP = gp[512 + j]; ginP = gp[1024 + j];
    }
    // dgi stores drain during barrier + next step's dots
    if (act) {
      size_t drow = ((size_t)b * TT + t) * 1536;
      dgiB[drow + j] = f2bf(dg0);
      dgiB[drow + 512 + j] = f2bf(dg1);
      dgiB[drow + 1024 + j] = f2bf(dg2);
    }
    if (ex) __syncthreads();
    gir = gir1; giz = giz1; gin = gin1;
    gir1 = girP; giz1 = gizP; gin1 = ginP;
  }
}

// fused: sum 4 K-split partials, AXPY (out = xi - alpha*g), denorm, loss partial
__global__ __launch_bounds__(256) void denorm_loss_fused_kernel(
    const float* __restrict__ P, const float* __restrict__ R,
    const float* __restrict__ alphaPtr, const float* __restrict__ stdev,
    const float* __restrict__ means, const float* __restrict__ y,
    float* __restrict__ outn, float* __restrict__ dout, float* __restrict__ loss) {
  int idx = blockIdx.x * 256 + threadIdx.x;
  int tid = threadIdx.x;
  int c = idx & 63;
  int bt = idx >> 6;
  int t = bt % TT, b = bt / TT;
  float al = alphaPtr[0];
  float val = P[idx] + P[OUTN + idx] + P[2 * (size_t)OUTN + idx] + P[3 * (size_t)OUTN + idx];
  float on = R[idx] - al * val;
  outn[idx] = on;
  float od = on * stdev[b * CIN + c] + means[b * CIN + c];
  dout[idx] = od;
  float diff = fabsf(od - y[((size_t)b * 240 + 48 + t) * CIN + c]);
  __shared__ float red[256];
  red[tid] = diff;
  __syncthreads();
  if (tid < 128) red[tid] += red[tid + 128];
  __syncthreads();
  if (tid < 64) red[tid] += red[tid + 64];
  __syncthreads();
  if (tid < 64) {
    float rv = red[tid];
    #pragma unroll
    for (int s = 32; s > 0; s >>= 1) rv += __shfl_down(rv, s);
    if (tid == 0) atomicAdd(loss, rv);
  }
}

// ---------------- host launch ----------------
extern "C" void kernel_launch(void* const* d_in, const int* in_sizes, int n_in, void* d_out,
                              int out_size, void* d_ws, size_t ws_size, hipStream_t stream) {
  const float* x_enc = (const float*)d_in[0];
  const float* batch_y = (const float*)d_in[2];
  const float* y_mark = (const float*)d_in[3];
  const float* hx_init = (const float*)d_in[4];
  const float* conv_w = (const float*)d_in[5];
  const float* tf_w = (const float*)d_in[6];
  const float* Wq = (const float*)d_in[7];
  const float* Wk = (const float*)d_in[8];
  const float* Wv = (const float*)d_in[9];
  const float* Wo = (const float*)d_in[10];
  const float* bq = (const float*)d_in[11];
  const float* bk = (const float*)d_in[12];
  const float* bv = (const float*)d_in[13];
  const float* bo = (const float*)d_in[14];
  const float* ln1_g = (const float*)d_in[15];
  const float* ln1_b = (const float*)d_in[16];
  const float* W1 = (const float*)d_in[17];
  const float* b1 = (const float*)d_in[18];
  const float* W2 = (const float*)d_in[19];
  const float* b2 = (const float*)d_in[20];
  const float* ln2_g = (const float*)d_in[21];
  const float* ln2_b = (const float*)d_in[22];
  const float* pl1_w = (const float*)d_in[23];
  const float* pl1_b = (const float*)d_in[24];
  const float* pl2_w = (const float*)d_in[25];
  const float* pl2_b = (const float*)d_in[26];
  const float* proj_w = (const float*)d_in[27];
  const float* proj_b = (const float*)d_in[28];
  const float* gru_wih = (const float*)d_in[29];
  const float* gru_whh = (const float*)d_in[30];
  const float* gru_bih = (const float*)d_in[31];
  const float* gru_bhh = (const float*)d_in[32];
  const float* score_w = (const float*)d_in[33];
  const float* alpha = (const float*)d_in[34];
  float* dout = (float*)d_out;

  float* W = (float*)d_ws;
  size_t off = 0;
  float* means = W + off;   off += 2048;
  float* stdev = W + off;   off += 2048;
  float* lossacc = W + off; off += 64;
  float* preA = W + off;    off += (size_t)OUTN;
  float* outA = W + off;    off += (size_t)OUTN;
  float* outB = W + off;    off += (size_t)OUTN;
  float* corrupt = W + off; off += (size_t)OUTN;
  float* peT = W + off;     off += (size_t)TT * DM;   // PE table
  float* Wemb = W + off;    off += (size_t)KEMB * DM; // embed GEMM weights (persist)
  float* axp = W + off;     off += (size_t)4 * OUTN;  // K-split AXPY partials
  float* Xp = axp;  // alias: axp dead at embed time (written later by axpy_partial)
  signed char* whhJ = (signed char*)(W + off); off += 786432 / 4;
  float* sws = W + off;     off += 1536;
  unsigned long long* hqg = (unsigned long long*)(W + off); off += 2 * BATCH * 128 * 2;  // 8192 qwords
  float* emb = W + off;     off += MND;
  float* Kb = W + off;      off += 2 * MND;  // 2 K-split partials for O-proj / FF2
  float* gi_all = W + off;  off += (size_t)BATCH * TT * 1536;
  unsigned short* embB = (unsigned short*)(W + off);  off += MND / 2;
  unsigned short* qkvB = (unsigned short*)(W + off);  off += (size_t)BATCH * TT * 1536 / 2;
  unsigned short* attnOB = (unsigned short*)(W + off); off += MND / 2;
  unsigned short* FFbB = (unsigned short*)(W + off);  off += (size_t)BATCH * TT * DFF / 2;
  unsigned short* xcatB = (unsigned short*)(W + off); off += (size_t)BATCH * TT * 128 / 2;
  float* bqkv = W + off;    off += 2 * 1536;
  unsigned short* WxProjB = (unsigned short*)(W + off); off += (size_t)128 * 1536 / 2;
  unsigned short* wT = (unsigned short*)(W + off);
  const size_t SQ = (size_t)DM * DM;
  const size_t SFF = (size_t)DM * DFF;
  const size_t LAYER = 4 * SQ + 2 * SFF;
  unsigned short* wihB = wT + 2 * LAYER;
  off += (2 * LAYER + (size_t)1536 * 128) / 2 + 64;
  unsigned short* dgiB = qkvB;  // alias: qkvB dead after attention, reused for dgi

  const int M = BATCH * TT;  // 6144

  zero_loss_kernel<<<1, 64, 0, stream>>>(lossacc);
  zero_hqg_kernel<<<32, 256, 0, stream>>>(hqg);  // clear stale tags (graph-replay safety)
  pe_table_kernel<<<TT, DM, 0, stream>>>(peT);
  build_wemb_kernel<<<(KEMB * DM) / 256, 256, 0, stream>>>(conv_w, tf_w, Wemb);
  stats_kernel<<<BATCH, 64, 0, stream>>>(x_enc, means, stdev);
  pl1_kernel<<<dim3(TT, BATCH), 64, 0, stream>>>(x_enc, means, stdev, pl1_w, pl1_b, preA);
  pack_whh_q8_kernel<<<1536, 64, 0, stream>>>(gru_whh, whhJ, sws);
  pack_wxproj_kernel<<<(128 * 1536) / 256, 256, 0, stream>>>(gru_wih, WxProjB);
  concat_qkv_bias_kernel<<<dim3(6, 2), 256, 0, stream>>>(bq, bk, bv, bqkv);
  for (int l = 0; l < 2; l++) {
    unsigned short* base = wT + (size_t)l * LAYER;
    pack_transpose_bf16_kernel<<<dim3(8, 8), 256, 0, stream>>>(Wq + (size_t)l * SQ, base, DM, DM);
    pack_transpose_bf16_kernel<<<dim3(8, 8), 256, 0, stream>>>(Wk + (size_t)l * SQ, base + SQ, DM, DM);
    pack_transpose_bf16_kernel<<<dim3(8, 8), 256, 0, stream>>>(Wv + (size_t)l * SQ, base + 2 * SQ, DM, DM);
    pack_transpose_bf16_kernel<<<dim3(8, 8), 256, 0, stream>>>(Wo + (size_t)l * SQ, base + 3 * SQ, DM, DM);
    pack_transpose_bf16_kernel<<<dim3(8, 32), 256, 0, stream>>>(W1 + (size_t)l * SFF, base + 4 * SQ, DM, DFF);
    pack_transpose_bf16_kernel<<<dim3(32, 8), 256, 0, stream>>>(W2 + (size_t)l * SFF, base + 4 * SQ + SFF, DFF, DM);
  }
  pack_bf16_kernel<<<(1536 * 128) / 256, 256, 0, stream>>>(gru_wih, wihB, 1536 * 128);

  const float* pre = preA;
  float* outs[2] = {outA, outB};
  for (int s = 0; s < 2; s++) {
    pl2_kernel<<<dim3(TT, BATCH), 64, 0, stream>>>(pre, pl2_w, pl2_b, corrupt, xcatB);
    // embed as GEMM: Xp[6144x208] @ Wemb[208x512] + PE, writes emb f32 + embB bf16
    build_xp_kernel<<<(M * KEMB) / 256, 256, 0, stream>>>(corrupt, y_mark, Xp);
    gemm_kernel<0, 0, 0, 1><<<dim3(DM / 64, M / 64), 256, 0, stream>>>(
        Xp, Wemb, nullptr, emb, nullptr, peT, embB, M, DM, KEMB);
    for (int l = 0; l < 2; l++) {
      unsigned short* base = wT + (size_t)l * LAYER;
      gemm_bf16_kernel<0, 0, 1, 0><<<dim3(1536 / 128, M / 128), 256, 0, stream>>>(
          embB, base, bqkv + l * 1536, nullptr, qkvB, M, 1536, DM);
      attention_mfma_kernel<<<dim3(NH, BATCH), 256, 0, stream>>>(qkvB, attnOB);
      // O-proj: K-split x2 partials (384 blocks vs 192), bias folded into LN
      gemm_bf16_kernel<0, 0, 0, 1><<<dim3(DM / 128, M / 128, 2), 256, 0, stream>>>(
          attnOB, base + 3 * SQ, nullptr, Kb, nullptr, M, DM, DM);
      ln_residual_ks_kernel<<<M, 256, 0, stream>>>(emb, Kb, bo + l * DM, ln1_g + l * DM,
                                                   ln1_b + l * DM, embB);
      gemm_bf16_kernel<1, 0, 1, 0><<<dim3(DFF / 128, M / 128), 256, 0, stream>>>(
          embB, base + 4 * SQ, b1 + l * DFF, nullptr, FFbB, M, DFF, DM);
      // FF2: K-split x2 (K=2048 -> 1024 each, 384 blocks vs 192 with 64 serial k-steps)
      gemm_bf16_kernel<0, 0, 0, 1><<<dim3(DM / 128, M / 128, 2), 256, 0, stream>>>(
          FFbB, base + 4 * SQ + SFF, nullptr, Kb, nullptr, M, DM, DFF);
      ln_residual_ks_kernel<<<M, 256, 0, stream>>>(emb, Kb, b2 + l * DM, ln2_g + l * DM,
                                                   ln2_b + l * DM, embB);
    }
    // proj: writes cond bf16 straight into xcatB[:,64:128]
    gemm_kernel<1, 0, 1, 0><<<dim3(CIN / 64, M / 64), 256, 0, stream>>>(
        emb, proj_w, proj_b, nullptr, xcatB, nullptr, nullptr, M, CIN, DM);
    gemm_bf16_kernel<0, 1, 0, 0><<<dim3(1536 / 128, M / 128), 256, 0, stream>>>(
        xcatB, wihB, gru_bih, gi_all, nullptr, M, 1536, 128);
    langevin_scan_kernel<<<dim3(BATCH, 4), 1024, 0, stream>>>(
        gi_all, hx_init + (size_t)s * BATCH * DM, whhJ, sws, gru_bhh, score_w, dgiB, hqg,
        s * TT);
    // out = xi - alpha * dgi @ Wx^T : K-split partials (192 blocks) + fused epilogue
    axpy_partial_kernel<<<dim3(4, M / 128), 256, 0, stream>>>(dgiB, WxProjB, axp, M, 1536);
    denorm_loss_fused_kernel<<<OUTN / 256, 256, 0, stream>>>(
        axp, corrupt, alpha, stdev, means, batch_y, outs[s], dout, lossacc);
    pre = outs[s];
  }
  finalize_kernel<<<1, 1, 0, stream>>>(dout, lossacc);
}

// Round 11
// 2097.359 us; speedup vs baseline: 1.0714x; 1.0211x over previous
//
#include <hip/hip_runtime.h>
#include <math.h>

#define BATCH 32
#define TT    192
#define DM    512
#define CIN   64
#define SEQL  336
#define DFF   2048
#define NH    8
#define COF   0.1f
#define OUTN  (BATCH*TT*CIN)   // 393216
#define KEMB  208              // 192 conv + 4 mark + 12 zero-pad
#define MND   ((size_t)BATCH*TT*DM)  // 6144*512

typedef _Float16 h2_t __attribute__((ext_vector_type(2)));
union H2U { unsigned int u; h2_t h; };

typedef short bf16x8 __attribute__((ext_vector_type(8)));
typedef float f32x4 __attribute__((ext_vector_type(4)));
typedef unsigned int u32x4 __attribute__((ext_vector_type(4)));

__device__ __forceinline__ unsigned short f2bf(float v) {
  union { float f; unsigned int u; } a; a.f = v;
  unsigned int r = (a.u + 0x7fffu + ((a.u >> 16) & 1u)) >> 16;  // RNE
  return (unsigned short)r;
}

// async global->LDS 16B: lane l of the wave writes lds_base + l*16
__device__ __forceinline__ void gload16(const unsigned short* g, unsigned short* l) {
  __builtin_amdgcn_global_load_lds(
      (const __attribute__((address_space(1))) void*)g,
      (__attribute__((address_space(3))) void*)l, 16, 0, 0);
}

// signed 4x i8 dot product with i32 accumulate
__device__ __forceinline__ int sd4(unsigned int a, unsigned int b, int c) {
#if __has_builtin(__builtin_amdgcn_sdot4)
  return __builtin_amdgcn_sdot4((int)a, (int)b, c, false);
#else
  c += (int)(signed char)(a & 0xff) * (int)(signed char)(b & 0xff);
  c += (int)(signed char)((a >> 8) & 0xff) * (int)(signed char)((b >> 8) & 0xff);
  c += (int)(signed char)((a >> 16) & 0xff) * (int)(signed char)((b >> 16) & 0xff);
  c += (int)(signed char)(a >> 24) * (int)(signed char)(b >> 24);
  return c;
#endif
}

__device__ __forceinline__ int sd16(u32x4 w, u32x4 h, int acc) {
  acc = sd4(w[0], h[0], acc); acc = sd4(w[1], h[1], acc);
  acc = sd4(w[2], h[2], acc); acc = sd4(w[3], h[3], acc);
  return acc;
}

// quantize 4 floats (scale 127/8) into one packed i8x4 word
__device__ __forceinline__ unsigned int packq4(const float* hp) {
  int a = (int)rintf(hp[0] * 15.875f); a = a < -127 ? -127 : (a > 127 ? 127 : a);
  int b = (int)rintf(hp[1] * 15.875f); b = b < -127 ? -127 : (b > 127 ? 127 : b);
  int c = (int)rintf(hp[2] * 15.875f); c = c < -127 ? -127 : (c > 127 ? 127 : c);
  int d = (int)rintf(hp[3] * 15.875f); d = d < -127 ? -127 : (d > 127 ? 127 : d);
  return (unsigned int)((a & 0xff) | ((b & 0xff) << 8) | ((c & 0xff) << 16) |
                        ((d & 0xff) << 24));
}

// ---------------- merged setup kernel ----------------
// Segments (all multiples of 256 -> wave-uniform branch per block):
//  S0 pe-table 98304 | S1 Wemb 106496 | S2 WxProj 196608 | S3 wihB 196608
//  S4 qkv-bias concat 3072 | S5 hqg zero 8192 | S6 whh-q8 pack 98304 (64-lane rows)
//  S7 stats 2048 | S8 loss zero 256.  Total 709888 -> 2773 blocks.
#define SB0 98304
#define SB1 (SB0 + 106496)
#define SB2 (SB1 + 196608)
#define SB3 (SB2 + 196608)
#define SB4 (SB3 + 3072)
#define SB5 (SB4 + 8192)
#define SB6 (SB5 + 98304)
#define SB7 (SB6 + 2048)
#define SB8 (SB7 + 256)
__global__ __launch_bounds__(256) void setup_misc_kernel(
    const float* __restrict__ conv_w, const float* __restrict__ tf_w,
    const float* __restrict__ wih, const float* __restrict__ bq,
    const float* __restrict__ bk, const float* __restrict__ bv,
    const float* __restrict__ whh, const float* __restrict__ x_enc,
    float* __restrict__ peT, float* __restrict__ Wemb,
    unsigned short* __restrict__ WxProjB, unsigned short* __restrict__ wihB,
    float* __restrict__ bqkv, unsigned long long* __restrict__ hqg,
    signed char* __restrict__ whhJ, float* __restrict__ sws,
    float* __restrict__ means, float* __restrict__ stdev, float* __restrict__ loss) {
  int gidx = blockIdx.x * 256 + threadIdx.x;
  if (gidx < SB0) {
    // positional-encoding table (bit-identical formula)
    int t = gidx / DM, d = gidx % DM;
    int i2 = (d >> 1) * 2;
    float freq = expf((float)i2 * (-9.210340371976184f / (float)DM));
    float ang = (float)t * freq;
    peT[gidx] = (d & 1) ? cosf(ang) : sinf(ang);
  } else if (gidx < SB1) {
    int idx = gidx - SB0;
    int n = idx % DM, k = idx / DM;
    float v = 0.f;
    if (k < 192) v = conv_w[(size_t)k * DM + n];
    else if (k < 196) v = tf_w[(size_t)(k - 192) * DM + n];
    Wemb[idx] = v;
  } else if (gidx < SB2) {
    int idx = gidx - SB1;  // 128*1536
    int k = idx % 1536, n = idx / 1536;
    float v = (n < 64) ? wih[(size_t)k * 128 + n] : 0.f;
    WxProjB[idx] = f2bf(v);
  } else if (gidx < SB3) {
    int idx = gidx - SB2;  // 1536*128
    wihB[idx] = f2bf(wih[idx]);
  } else if (gidx < SB4) {
    int t = gidx - SB3;  // 2*1536
    int l = t / 1536, i = t % 1536;
    float v = (i < 512) ? bq[l * 512 + i]
                        : ((i < 1024) ? bk[l * 512 + i - 512] : bv[l * 512 + i - 1024]);
    bqkv[l * 1536 + i] = v;
  } else if (gidx < SB5) {
    hqg[gidx - SB4] = 0ull;
  } else if (gidx < SB6) {
    // whh i8 pack: row-per-wave (64 lanes), shfl_xor reduce within wave
    int t = gidx - SB5;
    int row = t >> 6, lane = t & 63;  // 0..1535 = g*512 + j
    const float* src = whh + (size_t)row * 512;
    float mx = 0.f;
    for (int k = lane; k < 512; k += 64) mx = fmaxf(mx, fabsf(src[k]));
    for (int off = 32; off > 0; off >>= 1) mx = fmaxf(mx, __shfl_xor(mx, off));
    float inv = (mx > 0.f) ? 127.f / mx : 0.f;
    if (lane == 0) sws[row] = (mx / 127.f) * (8.f / 127.f);
    int g = row >> 9, jj = row & 511;
    int quad = jj >> 7, jl = jj & 127;
    for (int k = lane; k < 512; k += 64) {
      int qv = (int)rintf(src[k] * inv);
      qv = qv < -127 ? -127 : (qv > 127 ? 127 : qv);
      int kh = k >> 6, u = (k >> 4) & 3, m = k & 15;
      whhJ[((size_t)(((quad * 128 + jl) * 8 + kh) * 4 + u) * 3 + g) * 16 + m] =
          (signed char)qv;
    }
  } else if (gidx < SB7) {
    int t = gidx - SB6;  // 32*64
    int b = t >> 6, c = t & 63;
    const float* xb = x_enc + (size_t)b * SEQL * CIN + c;
    float s = 0.f;
    for (int tt = 0; tt < SEQL; tt++) s += xb[tt * CIN];
    float mu = s * (1.f / SEQL);
    float s2 = 0.f;
    for (int tt = 0; tt < SEQL; tt++) { float d = xb[tt * CIN] - mu; s2 += d * d; }
    means[b * CIN + c] = mu;
    stdev[b * CIN + c] = sqrtf(s2 * (1.f / SEQL) + 1e-5f);
  } else if (gidx < SB8) {
    if (gidx == SB7) loss[0] = 0.f;
  }
}

// ---------------- merged weight transpose-pack (all 12 matrices, 1 launch) ----------------
// blockIdx.x in [0,1536): l = bid/768; r = bid%768:
//  r<256: Wq/Wk/Wv/Wo (64 tiles each); r<512: W1 (256 tiles); else W2 (256 tiles).
__global__ __launch_bounds__(256) void pack_all_weights_kernel(
    const float* __restrict__ Wq, const float* __restrict__ Wk,
    const float* __restrict__ Wv, const float* __restrict__ Wo,
    const float* __restrict__ W1, const float* __restrict__ W2,
    unsigned short* __restrict__ wT) {
  const size_t SQ = (size_t)DM * DM, SFF = (size_t)DM * DFF;
  const size_t LAYER = 4 * SQ + 2 * SFF;
  int bid = blockIdx.x;
  int l = bid / 768, r = bid % 768;
  const float* src;
  unsigned short* dst;
  int K_, N_, tile;
  if (r < 256) {
    int mi = r >> 6;
    tile = r & 63;
    const float* mats[4] = {Wq, Wk, Wv, Wo};
    src = mats[mi] + (size_t)l * SQ;
    dst = wT + (size_t)l * LAYER + (size_t)mi * SQ;
    K_ = DM; N_ = DM;
  } else if (r < 512) {
    tile = r - 256;
    src = W1 + (size_t)l * SFF;
    dst = wT + (size_t)l * LAYER + 4 * SQ;
    K_ = DM; N_ = DFF;
  } else {
    tile = r - 512;
    src = W2 + (size_t)l * SFF;
    dst = wT + (size_t)l * LAYER + 4 * SQ + SFF;
    K_ = DFF; N_ = DM;
  }
  int ktiles = K_ >> 6;
  int kb = (tile % ktiles) * 64, nb = (tile / ktiles) * 64;
  __shared__ unsigned short ts[64][65];
  int tid = threadIdx.x;
  int tn = tid & 63, tk = tid >> 6;
  #pragma unroll
  for (int i = 0; i < 16; i++) {
    int k = tk + i * 4;
    ts[k][tn] = f2bf(src[(size_t)(kb + k) * N_ + nb + tn]);
  }
  __syncthreads();
  int tk2 = tid & 63, tn2 = tid >> 6;
  #pragma unroll
  for (int i = 0; i < 16; i++) {
    int n = tn2 + i * 4;
    dst[(size_t)(nb + n) * K_ + kb + tk2] = ts[tk2][n];
  }
}

// ---------------- small utility kernels ----------------

__global__ void finalize_kernel(float* dout, const float* loss) {
  dout[OUTN] = loss[0] * (1.f / (float)OUTN);
}

// Xp[row=b*TT+t][208] = [corrupt[b][t-1] | corrupt[b][t] | corrupt[b][t+1] | mark | 0]
__global__ void build_xp_kernel(const float* __restrict__ corrupt,
                                const float* __restrict__ ymark, float* __restrict__ Xp) {
  int idx = blockIdx.x * 256 + threadIdx.x;  // 6144*208
  int col = idx % KEMB, row = idx / KEMB;
  int b = row / TT, t = row % TT;
  float v;
  if (col < 64) {
    int tm = (t + TT - 1) % TT;
    v = corrupt[((size_t)b * TT + tm) * CIN + col];
  } else if (col < 128) {
    v = corrupt[((size_t)b * TT + t) * CIN + (col - 64)];
  } else if (col < 192) {
    int tp = (t + 1) % TT;
    v = corrupt[((size_t)b * TT + tp) * CIN + (col - 128)];
  } else if (col < 196) {
    v = ymark[((size_t)b * 240 + 48 + t) * 4 + (col - 192)];
  } else {
    v = 0.f;
  }
  Xp[idx] = v;
}

__global__ void pl1_kernel(const float* __restrict__ x, const float* __restrict__ means,
                           const float* __restrict__ stdev, const float* __restrict__ w,
                           const float* __restrict__ bias, float* __restrict__ pre) {
  int p = blockIdx.x, b = blockIdx.y, c = threadIdx.x;  // 64 threads
  float mu = means[b * CIN + c];
  float inv = 1.f / stdev[b * CIN + c];
  const float* xb = x + (size_t)b * SEQL * CIN + c;
  const float* wp = w + p * SEQL;
  float acc = 0.f;
  for (int t = 0; t < SEQL; t++) acc += (xb[t * CIN] - mu) * wp[t];
  pre[((size_t)b * TT + p) * CIN + c] = acc * inv + bias[p];
}

// pl2: corrupt f32 + bf16 copy into xcatB[:,0:64]
__global__ void pl2_kernel(const float* __restrict__ pre, const float* __restrict__ w,
                           const float* __restrict__ bias, float* __restrict__ out,
                           unsigned short* __restrict__ xc) {
  int q = blockIdx.x, b = blockIdx.y, c = threadIdx.x;  // 64 threads
  const float* pb = pre + (size_t)b * TT * CIN + c;
  const float* wq = w + q * TT;
  float acc = 0.f;
  for (int p = 0; p < TT; p++) acc += pb[p * CIN] * wq[p];
  float val = acc + bias[q];
  size_t r = (size_t)b * TT + q;
  out[r * CIN + c] = val;
  xc[r * 128 + c] = f2bf(val);
}

// ---------------- fp32 GEMM ----------------
// XC=1: write bf16 into xcatB[:,64:128] (proj). EMB=1: add peT[t][col], write
// emb f32 + embB bf16 (embed conv-as-GEMM).
template <int TB, int RELU, int XC, int EMB>
__global__ __launch_bounds__(256) void gemm_kernel(const float* __restrict__ A,
                                                   const float* __restrict__ B,
                                                   const float* __restrict__ bias,
                                                   float* __restrict__ C,
                                                   unsigned short* __restrict__ Cx,
                                                   const float* __restrict__ PE,
                                                   unsigned short* __restrict__ Cb2,
                                                   int M, int N, int K) {
  __shared__ float As[16][68];
  __shared__ float Bs[16][68];
  int tid = threadIdx.x;
  int bn = blockIdx.x * 64, bm = blockIdx.y * 64;
  int tx = tid & 15, ty = tid >> 4;
  int row0 = ty * 4, col0 = tx * 4;
  float acc[4][4] = {};
  for (int k0 = 0; k0 < K; k0 += 16) {
    {
      int m = tid >> 2, kq = (tid & 3) << 2;
      float4 av = *(const float4*)&A[(size_t)(bm + m) * K + k0 + kq];
      As[kq + 0][m] = av.x; As[kq + 1][m] = av.y; As[kq + 2][m] = av.z; As[kq + 3][m] = av.w;
    }
    if (TB) {
      int n = tid >> 2, kq = (tid & 3) << 2;
      float4 bv = *(const float4*)&B[(size_t)(bn + n) * K + k0 + kq];
      Bs[kq + 0][n] = bv.x; Bs[kq + 1][n] = bv.y; Bs[kq + 2][n] = bv.z; Bs[kq + 3][n] = bv.w;
    } else {
      int kk = tid >> 4, nq = (tid & 15) << 2;
      float4 bv = *(const float4*)&B[(size_t)(k0 + kk) * N + bn + nq];
      *(float4*)&Bs[kk][nq] = bv;
    }
    __syncthreads();
    #pragma unroll
    for (int k = 0; k < 16; k++) {
      float4 a4 = *(const float4*)&As[k][row0];
      float4 b4 = *(const float4*)&Bs[k][col0];
      float a[4] = {a4.x, a4.y, a4.z, a4.w};
      float bb[4] = {b4.x, b4.y, b4.z, b4.w};
      #pragma unroll
      for (int i = 0; i < 4; i++)
        #pragma unroll
        for (int j = 0; j < 4; j++) acc[i][j] += a[i] * bb[j];
    }
    __syncthreads();
  }
  float bv[4] = {0.f, 0.f, 0.f, 0.f};
  if (bias) *(float4*)bv = *(const float4*)&bias[bn + col0];
  #pragma unroll
  for (int i = 0; i < 4; i++) {
    int row = bm + row0 + i;
    float pe[4] = {0.f, 0.f, 0.f, 0.f};
    if (EMB) {
      int t = row % TT;
      *(float4*)pe = *(const float4*)&PE[(size_t)t * DM + bn + col0];
    }
    float ov[4];
    #pragma unroll
    for (int j = 0; j < 4; j++) {
      float v = acc[i][j] + bv[j];
      if (EMB) v += pe[j];
      if (RELU) v = fmaxf(v, 0.f);
      ov[j] = v;
    }
    if (XC) {
      unsigned short xv[4];
      #pragma unroll
      for (int j = 0; j < 4; j++) xv[j] = f2bf(ov[j]);
      *(uint2*)&Cx[(size_t)row * 128 + 64 + bn + col0] = *(uint2*)xv;
    } else {
      *(float4*)&C[(size_t)row * N + bn + col0] = *(float4*)ov;
      if (EMB) {
        unsigned short xv[4];
        #pragma unroll
        for (int j = 0; j < 4; j++) xv[j] = f2bf(ov[j]);
        *(uint2*)&Cb2[(size_t)row * N + bn + col0] = *(uint2*)xv;
      }
    }
  }
}

// ---------------- bf16 MFMA GEMM (bf16 A, bf16 Bt [N][K]) ----------------
// PART=1: K-split over blockIdx.z (2 halves); writes f32 partials to
// C[z*M*N + ...], NO bias (consumer sums partials + bias).
template <int RELU, int WF32, int WBF16, int PART>
__global__ __launch_bounds__(256) void gemm_bf16_kernel(
    const unsigned short* __restrict__ A, const unsigned short* __restrict__ Bt,
    const float* __restrict__ bias, float* __restrict__ C, unsigned short* __restrict__ Cb,
    int M, int N, int K) {
  __shared__ __align__(16) unsigned short As[128 * 32];
  __shared__ __align__(16) unsigned short Bs[128 * 32];
  int tid = threadIdx.x;
  int bm = blockIdx.y * 128, bn = blockIdx.x * 128;
  int wave = tid >> 6, lane = tid & 63;
  int wm = (wave >> 1) * 64, wn = (wave & 1) * 64;
  int r15 = lane & 15, q = lane >> 4;
  f32x4 acc[4][4] = {};
  int srow = wave * 32 + (lane >> 2);
  int scol = (lane & 3) * 8;
  int kbeg = 0, kend = K;
  if (PART) {
    int kq = blockIdx.z;
    kbeg = kq * (K >> 1);
    kend = (kq + 1) * (K >> 1);
  }
  for (int k0 = kbeg; k0 < kend; k0 += 32) {
    gload16(&A[(size_t)(bm + srow) * K + k0 + scol], &As[(wave * 32) * 32]);
    gload16(&A[(size_t)(bm + srow + 16) * K + k0 + scol], &As[(wave * 32 + 16) * 32]);
    gload16(&Bt[(size_t)(bn + srow) * K + k0 + scol], &Bs[(wave * 32) * 32]);
    gload16(&Bt[(size_t)(bn + srow + 16) * K + k0 + scol], &Bs[(wave * 32 + 16) * 32]);
    __syncthreads();
    bf16x8 af[4], bfr[4];
    #pragma unroll
    for (int mi = 0; mi < 4; mi++)
      af[mi] = *(const bf16x8*)&As[(wm + mi * 16 + r15) * 32 + q * 8];
    #pragma unroll
    for (int ni = 0; ni < 4; ni++)
      bfr[ni] = *(const bf16x8*)&Bs[(wn + ni * 16 + r15) * 32 + q * 8];
    #pragma unroll
    for (int mi = 0; mi < 4; mi++)
      #pragma unroll
      for (int ni = 0; ni < 4; ni++)
        acc[mi][ni] =
            __builtin_amdgcn_mfma_f32_16x16x32_bf16(af[mi], bfr[ni], acc[mi][ni], 0, 0, 0);
    __syncthreads();
  }
  size_t pofs = PART ? (size_t)blockIdx.z * ((size_t)M * N) : 0;
  #pragma unroll
  for (int mi = 0; mi < 4; mi++) {
    #pragma unroll
    for (int ni = 0; ni < 4; ni++) {
      int col = bn + wn + ni * 16 + r15;
      float bv = (!PART && bias) ? bias[col] : 0.f;
      #pragma unroll
      for (int v = 0; v < 4; v++) {
        int row = bm + wm + mi * 16 + q * 4 + v;
        float val = acc[mi][ni][v] + bv;
        if (RELU) val = fmaxf(val, 0.f);
        if (PART) C[pofs + (size_t)row * N + col] = val;
        if (WF32) C[(size_t)row * N + col] = val;
        if (WBF16) Cb[(size_t)row * N + col] = f2bf(val);
      }
    }
  }
}

// K-split partial GEMM for the AXPY path: grid (4, M/128)
__global__ __launch_bounds__(256) void axpy_partial_kernel(
    const unsigned short* __restrict__ A, const unsigned short* __restrict__ Bt,
    float* __restrict__ P, int M, int K) {
  __shared__ __align__(16) unsigned short As[128 * 32];
  __shared__ __align__(16) unsigned short Bs[128 * 32];
  int tid = threadIdx.x;
  int kq = blockIdx.x;
  int bm = blockIdx.y * 128;
  int wave = tid >> 6, lane = tid & 63;
  int wm = (wave >> 1) * 64, wn = (wave & 1) * 64;
  int r15 = lane & 15, q = lane >> 4;
  f32x4 acc[4][4] = {};
  int srow = wave * 32 + (lane >> 2);
  int scol = (lane & 3) * 8;
  int kbeg = kq * (K >> 2), kend = (kq + 1) * (K >> 2);
  for (int k0 = kbeg; k0 < kend; k0 += 32) {
    gload16(&A[(size_t)(bm + srow) * K + k0 + scol], &As[(wave * 32) * 32]);
    gload16(&A[(size_t)(bm + srow + 16) * K + k0 + scol], &As[(wave * 32 + 16) * 32]);
    gload16(&Bt[(size_t)srow * K + k0 + scol], &Bs[(wave * 32) * 32]);
    gload16(&Bt[(size_t)(srow + 16) * K + k0 + scol], &Bs[(wave * 32 + 16) * 32]);
    __syncthreads();
    bf16x8 af[4], bfr[4];
    #pragma unroll
    for (int mi = 0; mi < 4; mi++)
      af[mi] = *(const bf16x8*)&As[(wm + mi * 16 + r15) * 32 + q * 8];
    #pragma unroll
    for (int ni = 0; ni < 4; ni++)
      bfr[ni] = *(const bf16x8*)&Bs[(wn + ni * 16 + r15) * 32 + q * 8];
    #pragma unroll
    for (int mi = 0; mi < 4; mi++)
      #pragma unroll
      for (int ni = 0; ni < 4; ni++)
        acc[mi][ni] =
            __builtin_amdgcn_mfma_f32_16x16x32_bf16(af[mi], bfr[ni], acc[mi][ni], 0, 0, 0);
    __syncthreads();
  }
  #pragma unroll
  for (int mi = 0; mi < 4; mi++) {
    #pragma unroll
    for (int ni = 0; ni < 4; ni++) {
      int col = wn + ni * 16 + r15;
      if (col < 64) {
        #pragma unroll
        for (int v = 0; v < 4; v++) {
          int row = bm + wm + mi * 16 + q * 4 + v;
          P[(size_t)kq * OUTN + (size_t)row * 64 + col] = acc[mi][ni][v];
        }
      }
    }
  }
}

// ---------------- MFMA attention: one block per (h,b) — R8-proven form ----------------
__global__ __launch_bounds__(256) void attention_mfma_kernel(
    const unsigned short* __restrict__ qkv, unsigned short* __restrict__ attnO) {
  __shared__ __align__(16) unsigned short Ks[192 * 72];
  __shared__ __align__(16) unsigned short Vt[64 * 200];
  __shared__ __align__(16) float Ps[4][16 * 36];
  int h = blockIdx.x, b = blockIdx.y;
  int tid = threadIdx.x, wave = tid >> 6, lane = tid & 63;
  int m = lane & 15, q = lane >> 4;
  const unsigned short* Qg = qkv + (size_t)b * TT * 1536 + h * 64;
  const unsigned short* Kg = Qg + 512;
  const unsigned short* Vg = Qg + 1024;
  for (int idx = tid; idx < 192 * 8; idx += 256) {
    int s = idx >> 3, ch = (idx & 7) * 8;
    *(uint4*)&Ks[s * 72 + ch] = *(const uint4*)&Kg[(size_t)s * 1536 + ch];
  }
  for (int idx = tid; idx < 96 * 8; idx += 256) {
    int sp = idx >> 3, co = (idx & 7) * 8;
    uint4 v0 = *(const uint4*)&Vg[(size_t)(2 * sp) * 1536 + co];
    uint4 v1 = *(const uint4*)&Vg[(size_t)(2 * sp + 1) * 1536 + co];
    const unsigned short* e0 = (const unsigned short*)&v0;
    const unsigned short* e1 = (const unsigned short*)&v1;
    unsigned int* vtw = (unsigned int*)Vt;
    #pragma unroll
    for (int u = 0; u < 8; u++)
      vtw[(co + u) * 100 + sp] = (unsigned int)e0[u] | ((unsigned int)e1[u] << 16);
  }
  __syncthreads();
  float* ps = Ps[wave];
  for (int tile = wave; tile < 12; tile += 4) {
    int t0 = tile * 16;
    bf16x8 qf0 = *(const bf16x8*)&Qg[(size_t)(t0 + m) * 1536 + q * 8];
    bf16x8 qf1 = *(const bf16x8*)&Qg[(size_t)(t0 + m) * 1536 + 32 + q * 8];
    f32x4 S[12];
    #pragma unroll
    for (int nt = 0; nt < 12; nt++) {
      bf16x8 kf0 = *(const bf16x8*)&Ks[(nt * 16 + m) * 72 + q * 8];
      bf16x8 kf1 = *(const bf16x8*)&Ks[(nt * 16 + m) * 72 + 32 + q * 8];
      f32x4 a = {0.f, 0.f, 0.f, 0.f};
      a = __builtin_amdgcn_mfma_f32_16x16x32_bf16(qf0, kf0, a, 0, 0, 0);
      a = __builtin_amdgcn_mfma_f32_16x16x32_bf16(qf1, kf1, a, 0, 0, 0);
      S[nt] = a;
    }
    float mx[4] = {-1e30f, -1e30f, -1e30f, -1e30f};
    #pragma unroll
    for (int nt = 0; nt < 12; nt++)
      #pragma unroll
      for (int v = 0; v < 4; v++) {
        S[nt][v] *= 0.125f;
        mx[v] = fmaxf(mx[v], S[nt][v]);
      }
    #pragma unroll
    for (int d = 1; d < 16; d <<= 1) {
      #pragma unroll
      for (int v = 0; v < 4; v++) mx[v] = fmaxf(mx[v], __shfl_xor(mx[v], d));
    }
    float sm[4] = {0.f, 0.f, 0.f, 0.f};
    #pragma unroll
    for (int nt = 0; nt < 12; nt++)
      #pragma unroll
      for (int v = 0; v < 4; v++) {
        float e = __expf(S[nt][v] - mx[v]);
        S[nt][v] = e;
        sm[v] += e;
      }
    #pragma unroll
    for (int d = 1; d < 16; d <<= 1) {
      #pragma unroll
      for (int v = 0; v < 4; v++) sm[v] += __shfl_xor(sm[v], d);
    }
    float inv[4];
    #pragma unroll
    for (int v = 0; v < 4; v++) inv[v] = 1.f / sm[v];
    f32x4 o[4] = {};
    for (int kc = 0; kc < 6; kc++) {
      asm volatile("s_waitcnt lgkmcnt(0)" ::: "memory");
      #pragma unroll
      for (int half = 0; half < 2; half++) {
        int nt = 2 * kc + half;
        #pragma unroll
        for (int v = 0; v < 4; v++) ps[(q * 4 + v) * 36 + half * 16 + m] = S[nt][v];
      }
      asm volatile("s_waitcnt lgkmcnt(0)" ::: "memory");
      float4 p0 = *(const float4*)&ps[m * 36 + q * 8];
      float4 p1 = *(const float4*)&ps[m * 36 + q * 8 + 4];
      unsigned short tmp[8];
      tmp[0] = f2bf(p0.x); tmp[1] = f2bf(p0.y); tmp[2] = f2bf(p0.z); tmp[3] = f2bf(p0.w);
      tmp[4] = f2bf(p1.x); tmp[5] = f2bf(p1.y); tmp[6] = f2bf(p1.z); tmp[7] = f2bf(p1.w);
      bf16x8 pf = *(bf16x8*)tmp;
      #pragma unroll
      for (int nt2 = 0; nt2 < 4; nt2++) {
        bf16x8 vf = *(const bf16x8*)&Vt[(nt2 * 16 + m) * 200 + kc * 32 + q * 8];
        o[nt2] = __builtin_amdgcn_mfma_f32_16x16x32_bf16(pf, vf, o[nt2], 0, 0, 0);
      }
    }
    #pragma unroll
    for (int nt2 = 0; nt2 < 4; nt2++)
      #pragma unroll
      for (int v = 0; v < 4; v++) {
        size_t row = (size_t)b * TT + t0 + q * 4 + v;
        attnO[row * 512 + h * 64 + nt2 * 16 + m] = f2bf(o[nt2][v] * inv[v]);
      }
  }
}

// ---------------- layernorm with residual (K-split partials), in-place on x ----------------
// res = P[0] + P[MND] + bias (sums the 2 K-split GEMM partials + output bias)
__global__ __launch_bounds__(256) void ln_residual_ks_kernel(float* __restrict__ x,
                                                             const float* __restrict__ P,
                                                             const float* __restrict__ bias,
                                                             const float* __restrict__ g,
                                                             const float* __restrict__ b,
                                                             unsigned short* __restrict__ xb) {
  int row = blockIdx.x, tid = threadIdx.x;
  __shared__ float red[256];
  float* xr = x + (size_t)row * DM;
  const float* p0 = P + (size_t)row * DM;
  const float* p1 = p0 + MND;
  float r0 = p0[tid] + p1[tid] + bias[tid];
  float r1 = p0[tid + 256] + p1[tid + 256] + bias[tid + 256];
  float v0 = xr[tid] + r0;
  float v1 = xr[tid + 256] + r1;
  red[tid] = v0 + v1;
  __syncthreads();
  if (tid < 128) red[tid] += red[tid + 128];
  __syncthreads();
  if (tid < 64) red[tid] += red[tid + 64];
  __syncthreads();
  float rv = red[tid & 63];
  #pragma unroll
  for (int s = 32; s > 0; s >>= 1) rv += __shfl_down(rv, s);
  float mu = __shfl(rv, 0) * (1.f / DM);
  __syncthreads();  // WAR: red reuse
  float d0 = v0 - mu, d1 = v1 - mu;
  red[tid] = d0 * d0 + d1 * d1;
  __syncthreads();
  if (tid < 128) red[tid] += red[tid + 128];
  __syncthreads();
  if (tid < 64) red[tid] += red[tid + 64];
  __syncthreads();
  rv = red[tid & 63];
  #pragma unroll
  for (int s = 32; s > 0; s >>= 1) rv += __shfl_down(rv, s);
  float rstd = rsqrtf(__shfl(rv, 0) * (1.f / DM) + 1e-5f);
  float o0 = d0 * rstd * g[tid] + b[tid];
  float o1 = d1 * rstd * g[tid + 256] + b[tid + 256];
  xr[tid] = o0;
  xr[tid + 256] = o1;
  xb[(size_t)row * DM + tid] = f2bf(o0);
  xb[(size_t)row * DM + tid + 256] = f2bf(o1);
}

// ---------------- Langevin scan: 4 blocks per batch (j-split) ----------------
// R2-proven design (~597us): exchange chain is the ~3.1us/step structural floor.
__global__ __launch_bounds__(1024, 4) void langevin_scan_kernel(
    const float* __restrict__ gi_all, const float* __restrict__ hx0,
    const signed char* __restrict__ whhJ, const float* __restrict__ sws,
    const float* __restrict__ bhh, const float* __restrict__ score_w,
    unsigned short* __restrict__ dgiB, unsigned long long* __restrict__ hqg, int tagBase) {
  int b = blockIdx.x, quad = blockIdx.y;
  int tid = threadIdx.x;
  __shared__ __align__(16) unsigned int hqp[2][160];  // [buf][kh*20 + r], r<16 used
  int jl = tid >> 3, kh = tid & 7;
  int j = quad * 128 + jl;
  bool act = (kh == 0);
  float bhr = 0.f, bhz = 0.f, bhn = 0.f, sw = 0.f, swr = 0.f, swz = 0.f, swn = 0.f, h = 0.f;
  if (act) {
    bhr = bhh[j]; bhz = bhh[512 + j]; bhn = bhh[1024 + j];
    sw = score_w[j] * COF;
    swr = sws[j]; swz = sws[512 + j]; swn = sws[1024 + j];
    h = hx0[(size_t)b * 512 + j];
  }
  if (tid < 128) {
    float4 hv = *(const float4*)&hx0[(size_t)b * 512 + tid * 4];
    float tmp[4] = {hv.x, hv.y, hv.z, hv.w};
    hqp[0][(tid >> 4) * 20 + (tid & 15)] = packq4(tmp);
  }
  const u32x4* wbase = (const u32x4*)whhJ + (size_t)((quad * 128 + jl) * 8 + kh) * 12;
  u32x4 wreg[12];
  #pragma unroll
  for (int i = 0; i < 12; i++) wreg[i] = wbase[i];
  #pragma unroll
  for (int i = 0; i < 12; i++) asm volatile("" : "+v"(wreg[i]));
  // prefetch gi for t=0 and t=1 (distance-2 pipeline)
  float gir = 0.f, giz = 0.f, gin = 0.f, gir1 = 0.f, giz1 = 0.f, gin1 = 0.f;
  if (act) {
    const float* g0 = &gi_all[(size_t)b * TT * 1536];
    gir = g0[j]; giz = g0[512 + j]; gin = g0[1024 + j];
    const float* g1 = g0 + 1536;
    gir1 = g1[j]; giz1 = g1[512 + j]; gin1 = g1[1024 + j];
  }
  __syncthreads();
  for (int t = 0; t < TT; t++) {
    int rb = t & 1;
    int ir = 0, iz = 0, in_ = 0;
    #pragma unroll
    for (int u = 0; u < 4; u++) {
      u32x4 hqv = *(const u32x4*)&hqp[rb][kh * 20 + u * 4];
      ir = sd16(wreg[u * 3 + 0], hqv, ir);
      iz = sd16(wreg[u * 3 + 1], hqv, iz);
      in_ = sd16(wreg[u * 3 + 2], hqv, in_);
    }
    #pragma unroll
    for (int d = 1; d < 8; d <<= 1) {
      ir += __shfl_xor(ir, d);
      iz += __shfl_xor(iz, d);
      in_ += __shfl_xor(in_, d);
    }
    int qv = 0;
    float r = 0.f, z = 0.f, n = 0.f, hnv = 0.f, hj = 0.f;
    if (act) {
      float gr = (float)ir * swr, gz = (float)iz * swz, gn2 = (float)in_ * swn;
      r = 1.f / (1.f + expf(-(gir + gr + bhr)));
      z = 1.f / (1.f + expf(-(giz + gz + bhz)));
      hnv = gn2 + bhn;
      n = tanhf(gin + r * hnv);
      hj = h;
      h = (1.f - z) * n + z * hj;
      int q = (int)rintf(h * 15.875f);
      qv = q < -127 ? -127 : (q > 127 ? 127 : q);
    }
    // gather 4 consecutive j's i8 into owner lanes (tid%32==0) via in-wave shuffles
    int l = tid & 63;
    int q1 = __shfl(qv, (l + 8) & 63);
    int q2 = __shfl(qv, (l + 16) & 63);
    int q3 = __shfl(qv, (l + 24) & 63);
    bool ex = (t + 1 < TT);
    int wb = (t + 1) & 1;
    unsigned tag = (unsigned)(tagBase + t + 1);
    if (ex && (tid & 31) == 0) {
      unsigned word = (unsigned)(qv & 0xff) | ((unsigned)(q1 & 0xff) << 8) |
                      ((unsigned)(q2 & 0xff) << 16) | ((unsigned)(q3 & 0xff) << 24);
      int w = quad * 32 + (tid >> 5);
      hqp[wb][(w >> 4) * 20 + (w & 15)] = word;
      __hip_atomic_store(&hqg[((size_t)wb * BATCH + b) * 128 + w],
                         ((unsigned long long)tag << 32) | (unsigned long long)word,
                         __ATOMIC_RELAXED, __HIP_MEMORY_SCOPE_AGENT);
    }
    // gradient math off the publish->poll chain (pure VALU, overlaps store ack)
    float dg0 = 0.f, dg1 = 0.f, dg2 = 0.f;
    if (act) {
      float dinn = sw * (1.f - z) * (1.f - n * n);
      dg0 = dinn * hnv * r * (1.f - r);
      dg1 = sw * (hj - n) * z * (1.f - z);
      dg2 = dinn;
    }
    if (ex && kh == 1 && jl < 96) {
      int o = jl >> 5;
      int oq = (quad + 1 + o) & 3;
      int w = oq * 32 + (jl & 31);
      unsigned long long* p = &hqg[((size_t)wb * BATCH + b) * 128 + w];
      unsigned long long v = __hip_atomic_load(p, __ATOMIC_RELAXED, __HIP_MEMORY_SCOPE_AGENT);
      while ((unsigned)(v >> 32) != tag) {
        __builtin_amdgcn_s_sleep(1);
        v = __hip_atomic_load(p, __ATOMIC_RELAXED, __HIP_MEMORY_SCOPE_AGENT);
      }
      hqp[wb][(w >> 4) * 20 + (w & 15)] = (unsigned)v;
    }
    // keep the following VMEM ops AFTER the poll so its vmcnt(0) never waits on them
    __builtin_amdgcn_sched_barrier(0);
    // gi prefetch for t+2 (distance 2: fully hidden, off every poll's chain)
    float girP = 0.f, gizP = 0.f, ginP = 0.f;
    if (act && t + 2 < TT) {
      const float* gp = &gi_all[((size_t)b * TT + t + 2) * 1536];
      girP = gp[j]; gizP = gp[512 + j]; ginP = gp[1024 + j];
    }
    // dgi stores drain during barrier + next step's dots
    if (act) {
      size_t drow = ((size_t)b * TT + t) * 1536;
      dgiB[drow + j] = f2bf(dg0);
      dgiB[drow + 512 + j] = f2bf(dg1);
      dgiB[drow + 1024 + j] = f2bf(dg2);
    }
    if (ex) __syncthreads();
    gir = gir1; giz = giz1; gin = gin1;
    gir1 = girP; giz1 = gizP; gin1 = ginP;
  }
}

// fused: sum 4 K-split partials, AXPY (out = xi - alpha*g), denorm, loss partial
__global__ __launch_bounds__(256) void denorm_loss_fused_kernel(
    const float* __restrict__ P, const float* __restrict__ R,
    const float* __restrict__ alphaPtr, const float* __restrict__ stdev,
    const float* __restrict__ means, const float* __restrict__ y,
    float* __restrict__ outn, float* __restrict__ dout, float* __restrict__ loss) {
  int idx = blockIdx.x * 256 + threadIdx.x;
  int tid = threadIdx.x;
  int c = idx & 63;
  int bt = idx >> 6;
  int t = bt % TT, b = bt / TT;
  float al = alphaPtr[0];
  float val = P[idx] + P[OUTN + idx] + P[2 * (size_t)OUTN + idx] + P[3 * (size_t)OUTN + idx];
  float on = R[idx] - al * val;
  outn[idx] = on;
  float od = on * stdev[b * CIN + c] + means[b * CIN + c];
  dout[idx] = od;
  float diff = fabsf(od - y[((size_t)b * 240 + 48 + t) * CIN + c]);
  __shared__ float red[256];
  red[tid] = diff;
  __syncthreads();
  if (tid < 128) red[tid] += red[tid + 128];
  __syncthreads();
  if (tid < 64) red[tid] += red[tid + 64];
  __syncthreads();
  if (tid < 64) {
    float rv = red[tid];
    #pragma unroll
    for (int s = 32; s > 0; s >>= 1) rv += __shfl_down(rv, s);
    if (tid == 0) atomicAdd(loss, rv);
  }
}

// ---------------- host launch ----------------
extern "C" void kernel_launch(void* const* d_in, const int* in_sizes, int n_in, void* d_out,
                              int out_size, void* d_ws, size_t ws_size, hipStream_t stream) {
  const float* x_enc = (const float*)d_in[0];
  const float* batch_y = (const float*)d_in[2];
  const float* y_mark = (const float*)d_in[3];
  const float* hx_init = (const float*)d_in[4];
  const float* conv_w = (const float*)d_in[5];
  const float* tf_w = (const float*)d_in[6];
  const float* Wq = (const float*)d_in[7];
  const float* Wk = (const float*)d_in[8];
  const float* Wv = (const float*)d_in[9];
  const float* Wo = (const float*)d_in[10];
  const float* bq = (const float*)d_in[11];
  const float* bk = (const float*)d_in[12];
  const float* bv = (const float*)d_in[13];
  const float* bo = (const float*)d_in[14];
  const float* ln1_g = (const float*)d_in[15];
  const float* ln1_b = (const float*)d_in[16];
  const float* W1 = (const float*)d_in[17];
  const float* b1 = (const float*)d_in[18];
  const float* W2 = (const float*)d_in[19];
  const float* b2 = (const float*)d_in[20];
  const float* ln2_g = (const float*)d_in[21];
  const float* ln2_b = (const float*)d_in[22];
  const float* pl1_w = (const float*)d_in[23];
  const float* pl1_b = (const float*)d_in[24];
  const float* pl2_w = (const float*)d_in[25];
  const float* pl2_b = (const float*)d_in[26];
  const float* proj_w = (const float*)d_in[27];
  const float* proj_b = (const float*)d_in[28];
  const float* gru_wih = (const float*)d_in[29];
  const float* gru_whh = (const float*)d_in[30];
  const float* gru_bih = (const float*)d_in[31];
  const float* gru_bhh = (const float*)d_in[32];
  const float* score_w = (const float*)d_in[33];
  const float* alpha = (const float*)d_in[34];
  float* dout = (float*)d_out;

  float* W = (float*)d_ws;
  size_t off = 0;
  float* means = W + off;   off += 2048;
  float* stdev = W + off;   off += 2048;
  float* lossacc = W + off; off += 64;
  float* preA = W + off;    off += (size_t)OUTN;
  float* outA = W + off;    off += (size_t)OUTN;
  float* outB = W + off;    off += (size_t)OUTN;
  float* corrupt = W + off; off += (size_t)OUTN;
  float* peT = W + off;     off += (size_t)TT * DM;   // PE table
  float* Wemb = W + off;    off += (size_t)KEMB * DM; // embed GEMM weights (persist)
  float* axp = W + off;     off += (size_t)4 * OUTN;  // K-split AXPY partials
  float* Xp = axp;  // alias: axp dead at embed time (written later by axpy_partial)
  signed char* whhJ = (signed char*)(W + off); off += 786432 / 4;
  float* sws = W + off;     off += 1536;
  unsigned long long* hqg = (unsigned long long*)(W + off); off += 2 * BATCH * 128 * 2;  // 8192 qwords
  float* emb = W + off;     off += MND;
  float* Kb = W + off;      off += 2 * MND;  // 2 K-split partials for O-proj / FF2
  float* gi_all = W + off;  off += (size_t)BATCH * TT * 1536;
  unsigned short* embB = (unsigned short*)(W + off);  off += MND / 2;
  unsigned short* qkvB = (unsigned short*)(W + off);  off += (size_t)BATCH * TT * 1536 / 2;
  unsigned short* attnOB = (unsigned short*)(W + off); off += MND / 2;
  unsigned short* FFbB = (unsigned short*)(W + off);  off += (size_t)BATCH * TT * DFF / 2;
  unsigned short* xcatB = (unsigned short*)(W + off); off += (size_t)BATCH * TT * 128 / 2;
  float* bqkv = W + off;    off += 2 * 1536;
  unsigned short* WxProjB = (unsigned short*)(W + off); off += (size_t)128 * 1536 / 2;
  unsigned short* wT = (unsigned short*)(W + off);
  const size_t SQ = (size_t)DM * DM;
  const size_t SFF = (size_t)DM * DFF;
  const size_t LAYER = 4 * SQ + 2 * SFF;
  unsigned short* wihB = wT + 2 * LAYER;
  off += (2 * LAYER + (size_t)1536 * 128) / 2 + 64;
  unsigned short* dgiB = qkvB;  // alias: qkvB dead after attention, reused for dgi

  const int M = BATCH * TT;  // 6144

  // merged setup: pe/wemb/wxproj/wih/concat/hqg-zero/whh-pack/stats/loss-zero (1 launch)
  setup_misc_kernel<<<SB8 / 256, 256, 0, stream>>>(
      conv_w, tf_w, gru_wih, bq, bk, bv, gru_whh, x_enc, peT, Wemb, WxProjB, wihB, bqkv,
      hqg, whhJ, sws, means, stdev, lossacc);
  pl1_kernel<<<dim3(TT, BATCH), 64, 0, stream>>>(x_enc, means, stdev, pl1_w, pl1_b, preA);
  // merged weight transpose-pack: all 12 matrices (1 launch, 1536 blocks)
  pack_all_weights_kernel<<<1536, 256, 0, stream>>>(Wq, Wk, Wv, Wo, W1, W2, wT);

  const float* pre = preA;
  float* outs[2] = {outA, outB};
  for (int s = 0; s < 2; s++) {
    pl2_kernel<<<dim3(TT, BATCH), 64, 0, stream>>>(pre, pl2_w, pl2_b, corrupt, xcatB);
    // embed as GEMM: Xp[6144x208] @ Wemb[208x512] + PE, writes emb f32 + embB bf16
    build_xp_kernel<<<(M * KEMB) / 256, 256, 0, stream>>>(corrupt, y_mark, Xp);
    gemm_kernel<0, 0, 0, 1><<<dim3(DM / 64, M / 64), 256, 0, stream>>>(
        Xp, Wemb, nullptr, emb, nullptr, peT, embB, M, DM, KEMB);
    for (int l = 0; l < 2; l++) {
      unsigned short* base = wT + (size_t)l * LAYER;
      gemm_bf16_kernel<0, 0, 1, 0><<<dim3(1536 / 128, M / 128), 256, 0, stream>>>(
          embB, base, bqkv + l * 1536, nullptr, qkvB, M, 1536, DM);
      attention_mfma_kernel<<<dim3(NH, BATCH), 256, 0, stream>>>(qkvB, attnOB);
      // O-proj: K-split x2 partials (384 blocks), bias folded into LN
      gemm_bf16_kernel<0, 0, 0, 1><<<dim3(DM / 128, M / 128, 2), 256, 0, stream>>>(
          attnOB, base + 3 * SQ, nullptr, Kb, nullptr, M, DM, DM);
      ln_residual_ks_kernel<<<M, 256, 0, stream>>>(emb, Kb, bo + l * DM, ln1_g + l * DM,
                                                   ln1_b + l * DM, embB);
      gemm_bf16_kernel<1, 0, 1, 0><<<dim3(DFF / 128, M / 128), 256, 0, stream>>>(
          embB, base + 4 * SQ, b1 + l * DFF, nullptr, FFbB, M, DFF, DM);
      // FF2: K-split x2 (K=2048 -> 1024 each, 384 blocks)
      gemm_bf16_kernel<0, 0, 0, 1><<<dim3(DM / 128, M / 128, 2), 256, 0, stream>>>(
          FFbB, base + 4 * SQ + SFF, nullptr, Kb, nullptr, M, DM, DFF);
      ln_residual_ks_kernel<<<M, 256, 0, stream>>>(emb, Kb, b2 + l * DM, ln2_g + l * DM,
                                                   ln2_b + l * DM, embB);
    }
    // proj: writes cond bf16 straight into xcatB[:,64:128]
    gemm_kernel<1, 0, 1, 0><<<dim3(CIN / 64, M / 64), 256, 0, stream>>>(
        emb, proj_w, proj_b, nullptr, xcatB, nullptr, nullptr, M, CIN, DM);
    gemm_bf16_kernel<0, 1, 0, 0><<<dim3(1536 / 128, M / 128), 256, 0, stream>>>(
        xcatB, wihB, gru_bih, gi_all, nullptr, M, 1536, 128);
    langevin_scan_kernel<<<dim3(BATCH, 4), 1024, 0, stream>>>(
        gi_all, hx_init + (size_t)s * BATCH * DM, whhJ, sws, gru_bhh, score_w, dgiB, hqg,
        s * TT);
    // out = xi - alpha * dgi @ Wx^T : K-split partials (192 blocks) + fused epilogue
    axpy_partial_kernel<<<dim3(4, M / 128), 256, 0, stream>>>(dgiB, WxProjB, axp, M, 1536);
    denorm_loss_fused_kernel<<<OUTN / 256, 256, 0, stream>>>(
        axp, corrupt, alpha, stdev, means, batch_y, outs[s], dout, lossacc);
    pre = outs[s];
  }
  finalize_kernel<<<1, 1, 0, stream>>>(dout, lossacc);
}

// Round 12
// 2078.059 us; speedup vs baseline: 1.0814x; 1.0093x over previous
//
#include <hip/hip_runtime.h>
#include <math.h>

#define BATCH 32
#define TT    192
#define DM    512
#define CIN   64
#define SEQL  336
#define DFF   2048
#define NH    8
#define COF   0.1f
#define OUTN  (BATCH*TT*CIN)   // 393216
#define KEMB  208              // 192 conv + 4 mark + 12 zero-pad
#define MND   ((size_t)BATCH*TT*DM)  // 6144*512

typedef _Float16 h2_t __attribute__((ext_vector_type(2)));
union H2U { unsigned int u; h2_t h; };

typedef short bf16x8 __attribute__((ext_vector_type(8)));
typedef float f32x4 __attribute__((ext_vector_type(4)));
typedef unsigned int u32x4 __attribute__((ext_vector_type(4)));

__device__ __forceinline__ unsigned short f2bf(float v) {
  union { float f; unsigned int u; } a; a.f = v;
  unsigned int r = (a.u + 0x7fffu + ((a.u >> 16) & 1u)) >> 16;  // RNE
  return (unsigned short)r;
}

// async global->LDS 16B: lane l of the wave writes lds_base + l*16
__device__ __forceinline__ void gload16(const unsigned short* g, unsigned short* l) {
  __builtin_amdgcn_global_load_lds(
      (const __attribute__((address_space(1))) void*)g,
      (__attribute__((address_space(3))) void*)l, 16, 0, 0);
}

// signed 4x i8 dot product with i32 accumulate
__device__ __forceinline__ int sd4(unsigned int a, unsigned int b, int c) {
#if __has_builtin(__builtin_amdgcn_sdot4)
  return __builtin_amdgcn_sdot4((int)a, (int)b, c, false);
#else
  c += (int)(signed char)(a & 0xff) * (int)(signed char)(b & 0xff);
  c += (int)(signed char)((a >> 8) & 0xff) * (int)(signed char)((b >> 8) & 0xff);
  c += (int)(signed char)((a >> 16) & 0xff) * (int)(signed char)((b >> 16) & 0xff);
  c += (int)(signed char)(a >> 24) * (int)(signed char)(b >> 24);
  return c;
#endif
}

__device__ __forceinline__ int sd16(u32x4 w, u32x4 h, int acc) {
  acc = sd4(w[0], h[0], acc); acc = sd4(w[1], h[1], acc);
  acc = sd4(w[2], h[2], acc); acc = sd4(w[3], h[3], acc);
  return acc;
}

// quantize 4 floats (scale 127/8) into one packed i8x4 word
__device__ __forceinline__ unsigned int packq4(const float* hp) {
  int a = (int)rintf(hp[0] * 15.875f); a = a < -127 ? -127 : (a > 127 ? 127 : a);
  int b = (int)rintf(hp[1] * 15.875f); b = b < -127 ? -127 : (b > 127 ? 127 : b);
  int c = (int)rintf(hp[2] * 15.875f); c = c < -127 ? -127 : (c > 127 ? 127 : c);
  int d = (int)rintf(hp[3] * 15.875f); d = d < -127 ? -127 : (d > 127 ? 127 : d);
  return (unsigned int)((a & 0xff) | ((b & 0xff) << 8) | ((c & 0xff) << 16) |
                        ((d & 0xff) << 24));
}

// ---------------- merged setup kernel ----------------
#define SB0 98304
#define SB1 (SB0 + 106496)
#define SB2 (SB1 + 196608)
#define SB3 (SB2 + 196608)
#define SB4 (SB3 + 3072)
#define SB5 (SB4 + 8192)
#define SB6 (SB5 + 98304)
#define SB7 (SB6 + 2048)
#define SB8 (SB7 + 256)
__global__ __launch_bounds__(256) void setup_misc_kernel(
    const float* __restrict__ conv_w, const float* __restrict__ tf_w,
    const float* __restrict__ wih, const float* __restrict__ bq,
    const float* __restrict__ bk, const float* __restrict__ bv,
    const float* __restrict__ whh, const float* __restrict__ x_enc,
    float* __restrict__ peT, float* __restrict__ Wemb,
    unsigned short* __restrict__ WxProjB, unsigned short* __restrict__ wihB,
    float* __restrict__ bqkv, unsigned long long* __restrict__ hqg,
    signed char* __restrict__ whhJ, float* __restrict__ sws,
    float* __restrict__ means, float* __restrict__ stdev, float* __restrict__ loss) {
  int gidx = blockIdx.x * 256 + threadIdx.x;
  if (gidx < SB0) {
    int t = gidx / DM, d = gidx % DM;
    int i2 = (d >> 1) * 2;
    float freq = expf((float)i2 * (-9.210340371976184f / (float)DM));
    float ang = (float)t * freq;
    peT[gidx] = (d & 1) ? cosf(ang) : sinf(ang);
  } else if (gidx < SB1) {
    int idx = gidx - SB0;
    int n = idx % DM, k = idx / DM;
    float v = 0.f;
    if (k < 192) v = conv_w[(size_t)k * DM + n];
    else if (k < 196) v = tf_w[(size_t)(k - 192) * DM + n];
    Wemb[idx] = v;
  } else if (gidx < SB2) {
    int idx = gidx - SB1;  // 128*1536
    int k = idx % 1536, n = idx / 1536;
    float v = (n < 64) ? wih[(size_t)k * 128 + n] : 0.f;
    WxProjB[idx] = f2bf(v);
  } else if (gidx < SB3) {
    int idx = gidx - SB2;  // 1536*128
    wihB[idx] = f2bf(wih[idx]);
  } else if (gidx < SB4) {
    int t = gidx - SB3;  // 2*1536
    int l = t / 1536, i = t % 1536;
    float v = (i < 512) ? bq[l * 512 + i]
                        : ((i < 1024) ? bk[l * 512 + i - 512] : bv[l * 512 + i - 1024]);
    bqkv[l * 1536 + i] = v;
  } else if (gidx < SB5) {
    hqg[gidx - SB4] = 0ull;
  } else if (gidx < SB6) {
    int t = gidx - SB5;
    int row = t >> 6, lane = t & 63;  // 0..1535 = g*512 + j
    const float* src = whh + (size_t)row * 512;
    float mx = 0.f;
    for (int k = lane; k < 512; k += 64) mx = fmaxf(mx, fabsf(src[k]));
    for (int off = 32; off > 0; off >>= 1) mx = fmaxf(mx, __shfl_xor(mx, off));
    float inv = (mx > 0.f) ? 127.f / mx : 0.f;
    if (lane == 0) sws[row] = (mx / 127.f) * (8.f / 127.f);
    int g = row >> 9, jj = row & 511;
    int quad = jj >> 7, jl = jj & 127;
    for (int k = lane; k < 512; k += 64) {
      int qv = (int)rintf(src[k] * inv);
      qv = qv < -127 ? -127 : (qv > 127 ? 127 : qv);
      int kh = k >> 6, u = (k >> 4) & 3, m = k & 15;
      whhJ[((size_t)(((quad * 128 + jl) * 8 + kh) * 4 + u) * 3 + g) * 16 + m] =
          (signed char)qv;
    }
  } else if (gidx < SB7) {
    int t = gidx - SB6;  // 32*64
    int b = t >> 6, c = t & 63;
    const float* xb = x_enc + (size_t)b * SEQL * CIN + c;
    float s = 0.f;
    for (int tt = 0; tt < SEQL; tt++) s += xb[tt * CIN];
    float mu = s * (1.f / SEQL);
    float s2 = 0.f;
    for (int tt = 0; tt < SEQL; tt++) { float d = xb[tt * CIN] - mu; s2 += d * d; }
    means[b * CIN + c] = mu;
    stdev[b * CIN + c] = sqrtf(s2 * (1.f / SEQL) + 1e-5f);
  } else if (gidx < SB8) {
    if (gidx == SB7) loss[0] = 0.f;
  }
}

// ---------------- merged weight transpose-pack (all 12 matrices, 1 launch) ----------------
__global__ __launch_bounds__(256) void pack_all_weights_kernel(
    const float* __restrict__ Wq, const float* __restrict__ Wk,
    const float* __restrict__ Wv, const float* __restrict__ Wo,
    const float* __restrict__ W1, const float* __restrict__ W2,
    unsigned short* __restrict__ wT) {
  const size_t SQ = (size_t)DM * DM, SFF = (size_t)DM * DFF;
  const size_t LAYER = 4 * SQ + 2 * SFF;
  int bid = blockIdx.x;
  int l = bid / 768, r = bid % 768;
  const float* src;
  unsigned short* dst;
  int K_, N_, tile;
  if (r < 256) {
    int mi = r >> 6;
    tile = r & 63;
    const float* mats[4] = {Wq, Wk, Wv, Wo};
    src = mats[mi] + (size_t)l * SQ;
    dst = wT + (size_t)l * LAYER + (size_t)mi * SQ;
    K_ = DM; N_ = DM;
  } else if (r < 512) {
    tile = r - 256;
    src = W1 + (size_t)l * SFF;
    dst = wT + (size_t)l * LAYER + 4 * SQ;
    K_ = DM; N_ = DFF;
  } else {
    tile = r - 512;
    src = W2 + (size_t)l * SFF;
    dst = wT + (size_t)l * LAYER + 4 * SQ + SFF;
    K_ = DFF; N_ = DM;
  }
  int ktiles = K_ >> 6;
  int kb = (tile % ktiles) * 64, nb = (tile / ktiles) * 64;
  __shared__ unsigned short ts[64][65];
  int tid = threadIdx.x;
  int tn = tid & 63, tk = tid >> 6;
  #pragma unroll
  for (int i = 0; i < 16; i++) {
    int k = tk + i * 4;
    ts[k][tn] = f2bf(src[(size_t)(kb + k) * N_ + nb + tn]);
  }
  __syncthreads();
  int tk2 = tid & 63, tn2 = tid >> 6;
  #pragma unroll
  for (int i = 0; i < 16; i++) {
    int n = tn2 + i * 4;
    dst[(size_t)(nb + n) * K_ + kb + tk2] = ts[tk2][n];
  }
}

// ---------------- small utility kernels ----------------

__global__ void finalize_kernel(float* dout, const float* loss) {
  dout[OUTN] = loss[0] * (1.f / (float)OUTN);
}

__global__ void pl1_kernel(const float* __restrict__ x, const float* __restrict__ means,
                           const float* __restrict__ stdev, const float* __restrict__ w,
                           const float* __restrict__ bias, float* __restrict__ pre) {
  int p = blockIdx.x, b = blockIdx.y, c = threadIdx.x;  // 64 threads
  float mu = means[b * CIN + c];
  float inv = 1.f / stdev[b * CIN + c];
  const float* xb = x + (size_t)b * SEQL * CIN + c;
  const float* wp = w + p * SEQL;
  float acc = 0.f;
  for (int t = 0; t < SEQL; t++) acc += (xb[t * CIN] - mu) * wp[t];
  pre[((size_t)b * TT + p) * CIN + c] = acc * inv + bias[p];
}

// pl2: corrupt f32 + bf16 copy into xcatB[:,0:64]
__global__ void pl2_kernel(const float* __restrict__ pre, const float* __restrict__ w,
                           const float* __restrict__ bias, float* __restrict__ out,
                           unsigned short* __restrict__ xc) {
  int q = blockIdx.x, b = blockIdx.y, c = threadIdx.x;  // 64 threads
  const float* pb = pre + (size_t)b * TT * CIN + c;
  const float* wq = w + q * TT;
  float acc = 0.f;
  for (int p = 0; p < TT; p++) acc += pb[p * CIN] * wq[p];
  float val = acc + bias[q];
  size_t r = (size_t)b * TT + q;
  out[r * CIN + c] = val;
  xc[r * 128 + c] = f2bf(val);
}

// ---------------- fp32 GEMM ----------------
// XC=1: write bf16 into xcatB[:,64:128] (proj).
// EMB=1: A is gathered DIRECTLY from corrupt[b][t+-1]/ymark (circular conv as
// GEMM, build_xp eliminated); adds peT[t][col]; writes emb f32 + embB bf16.
template <int TB, int RELU, int XC, int EMB>
__global__ __launch_bounds__(256) void gemm_kernel(const float* __restrict__ A,
                                                   const float* __restrict__ B,
                                                   const float* __restrict__ bias,
                                                   float* __restrict__ C,
                                                   unsigned short* __restrict__ Cx,
                                                   const float* __restrict__ PE,
                                                   unsigned short* __restrict__ Cb2,
                                                   const float* __restrict__ ymk,
                                                   int M, int N, int K) {
  __shared__ float As[16][68];
  __shared__ float Bs[16][68];
  int tid = threadIdx.x;
  int bn = blockIdx.x * 64, bm = blockIdx.y * 64;
  int tx = tid & 15, ty = tid >> 4;
  int row0 = ty * 4, col0 = tx * 4;
  float acc[4][4] = {};
  for (int k0 = 0; k0 < K; k0 += 16) {
    {
      int m = tid >> 2, kq = (tid & 3) << 2;
      int row = bm + m, k = k0 + kq;
      float4 av;
      if (EMB) {
        int bb = row / TT, t = row % TT;
        if (k < 192) {
          int slot = k >> 6;
          int ts = (slot == 0) ? (t + TT - 1) % TT : ((slot == 1) ? t : (t + 1) % TT);
          av = *(const float4*)&A[((size_t)bb * TT + ts) * CIN + (k & 63)];
        } else if (k < 196) {
          av = *(const float4*)&ymk[((size_t)bb * 240 + 48 + t) * 4];
        } else {
          av = make_float4(0.f, 0.f, 0.f, 0.f);
        }
      } else {
        av = *(const float4*)&A[(size_t)row * K + k];
      }
      As[kq + 0][m] = av.x; As[kq + 1][m] = av.y; As[kq + 2][m] = av.z; As[kq + 3][m] = av.w;
    }
    if (TB) {
      int n = tid >> 2, kq = (tid & 3) << 2;
      float4 bv = *(const float4*)&B[(size_t)(bn + n) * K + k0 + kq];
      Bs[kq + 0][n] = bv.x; Bs[kq + 1][n] = bv.y; Bs[kq + 2][n] = bv.z; Bs[kq + 3][n] = bv.w;
    } else {
      int kk = tid >> 4, nq = (tid & 15) << 2;
      float4 bv = *(const float4*)&B[(size_t)(k0 + kk) * N + bn + nq];
      *(float4*)&Bs[kk][nq] = bv;
    }
    __syncthreads();
    #pragma unroll
    for (int k = 0; k < 16; k++) {
      float4 a4 = *(const float4*)&As[k][row0];
      float4 b4 = *(const float4*)&Bs[k][col0];
      float a[4] = {a4.x, a4.y, a4.z, a4.w};
      float bb[4] = {b4.x, b4.y, b4.z, b4.w};
      #pragma unroll
      for (int i = 0; i < 4; i++)
        #pragma unroll
        for (int j = 0; j < 4; j++) acc[i][j] += a[i] * bb[j];
    }
    __syncthreads();
  }
  float bv[4] = {0.f, 0.f, 0.f, 0.f};
  if (bias) *(float4*)bv = *(const float4*)&bias[bn + col0];
  #pragma unroll
  for (int i = 0; i < 4; i++) {
    int row = bm + row0 + i;
    float pe[4] = {0.f, 0.f, 0.f, 0.f};
    if (EMB) {
      int t = row % TT;
      *(float4*)pe = *(const float4*)&PE[(size_t)t * DM + bn + col0];
    }
    float ov[4];
    #pragma unroll
    for (int j = 0; j < 4; j++) {
      float v = acc[i][j] + bv[j];
      if (EMB) v += pe[j];
      if (RELU) v = fmaxf(v, 0.f);
      ov[j] = v;
    }
    if (XC) {
      unsigned short xv[4];
      #pragma unroll
      for (int j = 0; j < 4; j++) xv[j] = f2bf(ov[j]);
      *(uint2*)&Cx[(size_t)row * 128 + 64 + bn + col0] = *(uint2*)xv;
    } else {
      *(float4*)&C[(size_t)row * N + bn + col0] = *(float4*)ov;
      if (EMB) {
        unsigned short xv[4];
        #pragma unroll
        for (int j = 0; j < 4; j++) xv[j] = f2bf(ov[j]);
        *(uint2*)&Cb2[(size_t)row * N + bn + col0] = *(uint2*)xv;
      }
    }
  }
}

// ---------------- bf16 MFMA GEMM (bf16 A, bf16 Bt [N][K]) ----------------
// PART=1: K-split over blockIdx.z (2 halves); writes f32 partials.
template <int RELU, int WF32, int WBF16, int PART>
__global__ __launch_bounds__(256) void gemm_bf16_kernel(
    const unsigned short* __restrict__ A, const unsigned short* __restrict__ Bt,
    const float* __restrict__ bias, float* __restrict__ C, unsigned short* __restrict__ Cb,
    int M, int N, int K) {
  __shared__ __align__(16) unsigned short As[128 * 32];
  __shared__ __align__(16) unsigned short Bs[128 * 32];
  int tid = threadIdx.x;
  int bm = blockIdx.y * 128, bn = blockIdx.x * 128;
  int wave = tid >> 6, lane = tid & 63;
  int wm = (wave >> 1) * 64, wn = (wave & 1) * 64;
  int r15 = lane & 15, q = lane >> 4;
  f32x4 acc[4][4] = {};
  int srow = wave * 32 + (lane >> 2);
  int scol = (lane & 3) * 8;
  int kbeg = 0, kend = K;
  if (PART) {
    int kq = blockIdx.z;
    kbeg = kq * (K >> 1);
    kend = (kq + 1) * (K >> 1);
  }
  for (int k0 = kbeg; k0 < kend; k0 += 32) {
    gload16(&A[(size_t)(bm + srow) * K + k0 + scol], &As[(wave * 32) * 32]);
    gload16(&A[(size_t)(bm + srow + 16) * K + k0 + scol], &As[(wave * 32 + 16) * 32]);
    gload16(&Bt[(size_t)(bn + srow) * K + k0 + scol], &Bs[(wave * 32) * 32]);
    gload16(&Bt[(size_t)(bn + srow + 16) * K + k0 + scol], &Bs[(wave * 32 + 16) * 32]);
    __syncthreads();
    bf16x8 af[4], bfr[4];
    #pragma unroll
    for (int mi = 0; mi < 4; mi++)
      af[mi] = *(const bf16x8*)&As[(wm + mi * 16 + r15) * 32 + q * 8];
    #pragma unroll
    for (int ni = 0; ni < 4; ni++)
      bfr[ni] = *(const bf16x8*)&Bs[(wn + ni * 16 + r15) * 32 + q * 8];
    #pragma unroll
    for (int mi = 0; mi < 4; mi++)
      #pragma unroll
      for (int ni = 0; ni < 4; ni++)
        acc[mi][ni] =
            __builtin_amdgcn_mfma_f32_16x16x32_bf16(af[mi], bfr[ni], acc[mi][ni], 0, 0, 0);
    __syncthreads();
  }
  size_t pofs = PART ? (size_t)blockIdx.z * ((size_t)M * N) : 0;
  #pragma unroll
  for (int mi = 0; mi < 4; mi++) {
    #pragma unroll
    for (int ni = 0; ni < 4; ni++) {
      int col = bn + wn + ni * 16 + r15;
      float bv = (!PART && bias) ? bias[col] : 0.f;
      #pragma unroll
      for (int v = 0; v < 4; v++) {
        int row = bm + wm + mi * 16 + q * 4 + v;
        float val = acc[mi][ni][v] + bv;
        if (RELU) val = fmaxf(val, 0.f);
        if (PART) C[pofs + (size_t)row * N + col] = val;
        if (WF32) C[(size_t)row * N + col] = val;
        if (WBF16) Cb[(size_t)row * N + col] = f2bf(val);
      }
    }
  }
}

// K-split partial GEMM for the AXPY path: grid (4, M/128)
__global__ __launch_bounds__(256) void axpy_partial_kernel(
    const unsigned short* __restrict__ A, const unsigned short* __restrict__ Bt,
    float* __restrict__ P, int M, int K) {
  __shared__ __align__(16) unsigned short As[128 * 32];
  __shared__ __align__(16) unsigned short Bs[128 * 32];
  int tid = threadIdx.x;
  int kq = blockIdx.x;
  int bm = blockIdx.y * 128;
  int wave = tid >> 6, lane = tid & 63;
  int wm = (wave >> 1) * 64, wn = (wave & 1) * 64;
  int r15 = lane & 15, q = lane >> 4;
  f32x4 acc[4][4] = {};
  int srow = wave * 32 + (lane >> 2);
  int scol = (lane & 3) * 8;
  int kbeg = kq * (K >> 2), kend = (kq + 1) * (K >> 2);
  for (int k0 = kbeg; k0 < kend; k0 += 32) {
    gload16(&A[(size_t)(bm + srow) * K + k0 + scol], &As[(wave * 32) * 32]);
    gload16(&A[(size_t)(bm + srow + 16) * K + k0 + scol], &As[(wave * 32 + 16) * 32]);
    gload16(&Bt[(size_t)srow * K + k0 + scol], &Bs[(wave * 32) * 32]);
    gload16(&Bt[(size_t)(srow + 16) * K + k0 + scol], &Bs[(wave * 32 + 16) * 32]);
    __syncthreads();
    bf16x8 af[4], bfr[4];
    #pragma unroll
    for (int mi = 0; mi < 4; mi++)
      af[mi] = *(const bf16x8*)&As[(wm + mi * 16 + r15) * 32 + q * 8];
    #pragma unroll
    for (int ni = 0; ni < 4; ni++)
      bfr[ni] = *(const bf16x8*)&Bs[(wn + ni * 16 + r15) * 32 + q * 8];
    #pragma unroll
    for (int mi = 0; mi < 4; mi++)
      #pragma unroll
      for (int ni = 0; ni < 4; ni++)
        acc[mi][ni] =
            __builtin_amdgcn_mfma_f32_16x16x32_bf16(af[mi], bfr[ni], acc[mi][ni], 0, 0, 0);
    __syncthreads();
  }
  #pragma unroll
  for (int mi = 0; mi < 4; mi++) {
    #pragma unroll
    for (int ni = 0; ni < 4; ni++) {
      int col = wn + ni * 16 + r15;
      if (col < 64) {
        #pragma unroll
        for (int v = 0; v < 4; v++) {
          int row = bm + wm + mi * 16 + q * 4 + v;
          P[(size_t)kq * OUTN + (size_t)row * 64 + col] = acc[mi][ni][v];
        }
      }
    }
  }
}

// ---------------- MFMA attention: 768 threads, one Q-tile per wave ----------------
// R9 lesson: z-split duplicated K/V staging 3x (net loss). This form keeps
// staging at 1x and kills the serial tile loop: 12 waves, tile = wave.
// LDS 81KB -> 1 block/CU, 12 waves/CU (vs 8), serial tail 1 tile (vs 3).
// Per-tile math bit-identical to R8 form.
__global__ __launch_bounds__(768) void attention_mfma_kernel(
    const unsigned short* __restrict__ qkv, unsigned short* __restrict__ attnO) {
  __shared__ __align__(16) unsigned short Ks[192 * 72];
  __shared__ __align__(16) unsigned short Vt[64 * 200];
  __shared__ __align__(16) float Ps[12][16 * 36];
  int h = blockIdx.x, b = blockIdx.y;
  int tid = threadIdx.x, wave = tid >> 6, lane = tid & 63;
  int m = lane & 15, q = lane >> 4;
  const unsigned short* Qg = qkv + (size_t)b * TT * 1536 + h * 64;
  const unsigned short* Kg = Qg + 512;
  const unsigned short* Vg = Qg + 1024;
  for (int idx = tid; idx < 192 * 8; idx += 768) {
    int s = idx >> 3, ch = (idx & 7) * 8;
    *(uint4*)&Ks[s * 72 + ch] = *(const uint4*)&Kg[(size_t)s * 1536 + ch];
  }
  for (int idx = tid; idx < 96 * 8; idx += 768) {
    int sp = idx >> 3, co = (idx & 7) * 8;
    uint4 v0 = *(const uint4*)&Vg[(size_t)(2 * sp) * 1536 + co];
    uint4 v1 = *(const uint4*)&Vg[(size_t)(2 * sp + 1) * 1536 + co];
    const unsigned short* e0 = (const unsigned short*)&v0;
    const unsigned short* e1 = (const unsigned short*)&v1;
    unsigned int* vtw = (unsigned int*)Vt;
    #pragma unroll
    for (int u = 0; u < 8; u++)
      vtw[(co + u) * 100 + sp] = (unsigned int)e0[u] | ((unsigned int)e1[u] << 16);
  }
  __syncthreads();
  float* ps = Ps[wave];
  {
    int tile = wave;  // 12 waves, 12 tiles: no serial loop
    int t0 = tile * 16;
    bf16x8 qf0 = *(const bf16x8*)&Qg[(size_t)(t0 + m) * 1536 + q * 8];
    bf16x8 qf1 = *(const bf16x8*)&Qg[(size_t)(t0 + m) * 1536 + 32 + q * 8];
    f32x4 S[12];
    #pragma unroll
    for (int nt = 0; nt < 12; nt++) {
      bf16x8 kf0 = *(const bf16x8*)&Ks[(nt * 16 + m) * 72 + q * 8];
      bf16x8 kf1 = *(const bf16x8*)&Ks[(nt * 16 + m) * 72 + 32 + q * 8];
      f32x4 a = {0.f, 0.f, 0.f, 0.f};
      a = __builtin_amdgcn_mfma_f32_16x16x32_bf16(qf0, kf0, a, 0, 0, 0);
      a = __builtin_amdgcn_mfma_f32_16x16x32_bf16(qf1, kf1, a, 0, 0, 0);
      S[nt] = a;
    }
    float mx[4] = {-1e30f, -1e30f, -1e30f, -1e30f};
    #pragma unroll
    for (int nt = 0; nt < 12; nt++)
      #pragma unroll
      for (int v = 0; v < 4; v++) {
        S[nt][v] *= 0.125f;
        mx[v] = fmaxf(mx[v], S[nt][v]);
      }
    #pragma unroll
    for (int d = 1; d < 16; d <<= 1) {
      #pragma unroll
      for (int v = 0; v < 4; v++) mx[v] = fmaxf(mx[v], __shfl_xor(mx[v], d));
    }
    float sm[4] = {0.f, 0.f, 0.f, 0.f};
    #pragma unroll
    for (int nt = 0; nt < 12; nt++)
      #pragma unroll
      for (int v = 0; v < 4; v++) {
        float e = __expf(S[nt][v] - mx[v]);
        S[nt][v] = e;
        sm[v] += e;
      }
    #pragma unroll
    for (int d = 1; d < 16; d <<= 1) {
      #pragma unroll
      for (int v = 0; v < 4; v++) sm[v] += __shfl_xor(sm[v], d);
    }
    float inv[4];
    #pragma unroll
    for (int v = 0; v < 4; v++) inv[v] = 1.f / sm[v];
    f32x4 o[4] = {};
    for (int kc = 0; kc < 6; kc++) {
      asm volatile("s_waitcnt lgkmcnt(0)" ::: "memory");
      #pragma unroll
      for (int half = 0; half < 2; half++) {
        int nt = 2 * kc + half;
        #pragma unroll
        for (int v = 0; v < 4; v++) ps[(q * 4 + v) * 36 + half * 16 + m] = S[nt][v];
      }
      asm volatile("s_waitcnt lgkmcnt(0)" ::: "memory");
      float4 p0 = *(const float4*)&ps[m * 36 + q * 8];
      float4 p1 = *(const float4*)&ps[m * 36 + q * 8 + 4];
      unsigned short tmp[8];
      tmp[0] = f2bf(p0.x); tmp[1] = f2bf(p0.y); tmp[2] = f2bf(p0.z); tmp[3] = f2bf(p0.w);
      tmp[4] = f2bf(p1.x); tmp[5] = f2bf(p1.y); tmp[6] = f2bf(p1.z); tmp[7] = f2bf(p1.w);
      bf16x8 pf = *(bf16x8*)tmp;
      #pragma unroll
      for (int nt2 = 0; nt2 < 4; nt2++) {
        bf16x8 vf = *(const bf16x8*)&Vt[(nt2 * 16 + m) * 200 + kc * 32 + q * 8];
        o[nt2] = __builtin_amdgcn_mfma_f32_16x16x32_bf16(pf, vf, o[nt2], 0, 0, 0);
      }
    }
    #pragma unroll
    for (int nt2 = 0; nt2 < 4; nt2++)
      #pragma unroll
      for (int v = 0; v < 4; v++) {
        size_t row = (size_t)b * TT + t0 + q * 4 + v;
        attnO[row * 512 + h * 64 + nt2 * 16 + m] = f2bf(o[nt2][v] * inv[v]);
      }
  }
}

// ---------------- layernorm with residual (K-split partials), in-place on x ----------------
__global__ __launch_bounds__(256) void ln_residual_ks_kernel(float* __restrict__ x,
                                                             const float* __restrict__ P,
                                                             const float* __restrict__ bias,
                                                             const float* __restrict__ g,
                                                             const float* __restrict__ b,
                                                             unsigned short* __restrict__ xb) {
  int row = blockIdx.x, tid = threadIdx.x;
  __shared__ float red[256];
  float* xr = x + (size_t)row * DM;
  const float* p0 = P + (size_t)row * DM;
  const float* p1 = p0 + MND;
  float r0 = p0[tid] + p1[tid] + bias[tid];
  float r1 = p0[tid + 256] + p1[tid + 256] + bias[tid + 256];
  float v0 = xr[tid] + r0;
  float v1 = xr[tid + 256] + r1;
  red[tid] = v0 + v1;
  __syncthreads();
  if (tid < 128) red[tid] += red[tid + 128];
  __syncthreads();
  if (tid < 64) red[tid] += red[tid + 64];
  __syncthreads();
  float rv = red[tid & 63];
  #pragma unroll
  for (int s = 32; s > 0; s >>= 1) rv += __shfl_down(rv, s);
  float mu = __shfl(rv, 0) * (1.f / DM);
  __syncthreads();  // WAR: red reuse
  float d0 = v0 - mu, d1 = v1 - mu;
  red[tid] = d0 * d0 + d1 * d1;
  __syncthreads();
  if (tid < 128) red[tid] += red[tid + 128];
  __syncthreads();
  if (tid < 64) red[tid] += red[tid + 64];
  __syncthreads();
  rv = red[tid & 63];
  #pragma unroll
  for (int s = 32; s > 0; s >>= 1) rv += __shfl_down(rv, s);
  float rstd = rsqrtf(__shfl(rv, 0) * (1.f / DM) + 1e-5f);
  float o0 = d0 * rstd * g[tid] + b[tid];
  float o1 = d1 * rstd * g[tid + 256] + b[tid + 256];
  xr[tid] = o0;
  xr[tid + 256] = o1;
  xb[(size_t)row * DM + tid] = f2bf(o0);
  xb[(size_t)row * DM + tid + 256] = f2bf(o1);
}

// ---------------- Langevin scan: 4 blocks per batch (j-split) ----------------
// R2-proven design (~600us): exchange chain is the ~3.1us/step structural floor.
__global__ __launch_bounds__(1024, 4) void langevin_scan_kernel(
    const float* __restrict__ gi_all, const float* __restrict__ hx0,
    const signed char* __restrict__ whhJ, const float* __restrict__ sws,
    const float* __restrict__ bhh, const float* __restrict__ score_w,
    unsigned short* __restrict__ dgiB, unsigned long long* __restrict__ hqg, int tagBase) {
  int b = blockIdx.x, quad = blockIdx.y;
  int tid = threadIdx.x;
  __shared__ __align__(16) unsigned int hqp[2][160];  // [buf][kh*20 + r], r<16 used
  int jl = tid >> 3, kh = tid & 7;
  int j = quad * 128 + jl;
  bool act = (kh == 0);
  float bhr = 0.f, bhz = 0.f, bhn = 0.f, sw = 0.f, swr = 0.f, swz = 0.f, swn = 0.f, h = 0.f;
  if (act) {
    bhr = bhh[j]; bhz = bhh[512 + j]; bhn = bhh[1024 + j];
    sw = score_w[j] * COF;
    swr = sws[j]; swz = sws[512 + j]; swn = sws[1024 + j];
    h = hx0[(size_t)b * 512 + j];
  }
  if (tid < 128) {
    float4 hv = *(const float4*)&hx0[(size_t)b * 512 + tid * 4];
    float tmp[4] = {hv.x, hv.y, hv.z, hv.w};
    hqp[0][(tid >> 4) * 20 + (tid & 15)] = packq4(tmp);
  }
  const u32x4* wbase = (const u32x4*)whhJ + (size_t)((quad * 128 + jl) * 8 + kh) * 12;
  u32x4 wreg[12];
  #pragma unroll
  for (int i = 0; i < 12; i++) wreg[i] = wbase[i];
  #pragma unroll
  for (int i = 0; i < 12; i++) asm volatile("" : "+v"(wreg[i]));
  // prefetch gi for t=0 and t=1 (distance-2 pipeline)
  float gir = 0.f, giz = 0.f, gin = 0.f, gir1 = 0.f, giz1 = 0.f, gin1 = 0.f;
  if (act) {
    const float* g0 = &gi_all[(size_t)b * TT * 1536];
    gir = g0[j]; giz = g0[512 + j]; gin = g0[1024 + j];
    const float* g1 = g0 + 1536;
    gir1 = g1[j]; giz1 = g1[512 + j]; gin1 = g1[1024 + j];
  }
  __syncthreads();
  for (int t = 0; t < TT; t++) {
    int rb = t & 1;
    int ir = 0, iz = 0, in_ = 0;
    #pragma unroll
    for (int u = 0; u < 4; u++) {
      u32x4 hqv = *(const u32x4*)&hqp[rb][kh * 20 + u * 4];
      ir = sd16(wreg[u * 3 + 0], hqv, ir);
      iz = sd16(wreg[u * 3 + 1], hqv, iz);
      in_ = sd16(wreg[u * 3 + 2], hqv, in_);
    }
    #pragma unroll
    for (int d = 1; d < 8; d <<= 1) {
      ir += __shfl_xor(ir, d);
      iz += __shfl_xor(iz, d);
      in_ += __shfl_xor(in_, d);
    }
    int qv = 0;
    float r = 0.f, z = 0.f, n = 0.f, hnv = 0.f, hj = 0.f;
    if (act) {
      float gr = (float)ir * swr, gz = (float)iz * swz, gn2 = (float)in_ * swn;
      r = 1.f / (1.f + expf(-(gir + gr + bhr)));
      z = 1.f / (1.f + expf(-(giz + gz + bhz)));
      hnv = gn2 + bhn;
      n = tanhf(gin + r * hnv);
      hj = h;
      h = (1.f - z) * n + z * hj;
      int q = (int)rintf(h * 15.875f);
      qv = q < -127 ? -127 : (q > 127 ? 127 : q);
    }
    // gather 4 consecutive j's i8 into owner lanes (tid%32==0) via in-wave shuffles
    int l = tid & 63;
    int q1 = __shfl(qv, (l + 8) & 63);
    int q2 = __shfl(qv, (l + 16) & 63);
    int q3 = __shfl(qv, (l + 24) & 63);
    bool ex = (t + 1 < TT);
    int wb = (t + 1) & 1;
    unsigned tag = (unsigned)(tagBase + t + 1);
    if (ex && (tid & 31) == 0) {
      unsigned word = (unsigned)(qv & 0xff) | ((unsigned)(q1 & 0xff) << 8) |
                      ((unsigned)(q2 & 0xff) << 16) | ((unsigned)(q3 & 0xff) << 24);
      int w = quad * 32 + (tid >> 5);
      hqp[wb][(w >> 4) * 20 + (w & 15)] = word;
      __hip_atomic_store(&hqg[((size_t)wb * BATCH + b) * 128 + w],
                         ((unsigned long long)tag << 32) | (unsigned long long)word,
                         __ATOMIC_RELAXED, __HIP_MEMORY_SCOPE_AGENT);
    }
    // gradient math off the publish->poll chain (pure VALU, overlaps store ack)
    float dg0 = 0.f, dg1 = 0.f, dg2 = 0.f;
    if (act) {
      float dinn = sw * (1.f - z) * (1.f - n * n);
      dg0 = dinn * hnv * r * (1.f - r);
      dg1 = sw * (hj - n) * z * (1.f - z);
      dg2 = dinn;
    }
    if (ex && kh == 1 && jl < 96) {
      int o = jl >> 5;
      int oq = (quad + 1 + o) & 3;
      int w = oq * 32 + (jl & 31);
      unsigned long long* p = &hqg[((size_t)wb * BATCH + b) * 128 + w];
      unsigned long long v = __hip_atomic_load(p, __ATOMIC_RELAXED, __HIP_MEMORY_SCOPE_AGENT);
      while ((unsigned)(v >> 32) != tag) {
        __builtin_amdgcn_s_sleep(1);
        v = __hip_atomic_load(p, __ATOMIC_RELAXED, __HIP_MEMORY_SCOPE_AGENT);
      }
      hqp[wb][(w >> 4) * 20 + (w & 15)] = (unsigned)v;
    }
    // keep the following VMEM ops AFTER the poll so its vmcnt(0) never waits on them
    __builtin_amdgcn_sched_barrier(0);
    // gi prefetch for t+2 (distance 2: fully hidden, off every poll's chain)
    float girP = 0.f, gizP = 0.f, ginP = 0.f;
    if (act && t + 2 < TT) {
      const float* gp = &gi_all[((size_t)b * TT + t + 2) * 1536];
      girP = gp[j]; gizP = gp[512 + j]; ginP = gp[1024 + j];
    }
    // dgi stores drain during barrier + next step's dots
    if (act) {
      size_t drow = ((size_t)b * TT + t) * 1536;
      dgiB[drow + j] = f2bf(dg0);
      dgiB[drow + 512 + j] = f2bf(dg1);
      dgiB[drow + 1024 + j] = f2bf(dg2);
    }
    if (ex) __syncthreads();
    gir = gir1; giz = giz1; gin = gin1;
    gir1 = girP; giz1 = gizP; gin1 = ginP;
  }
}

// fused: sum 4 K-split partials, AXPY (out = xi - alpha*g), denorm, loss partial
__global__ __launch_bounds__(256) void denorm_loss_fused_kernel(
    const float* __restrict__ P, const float* __restrict__ R,
    const float* __restrict__ alphaPtr, const float* __restrict__ stdev,
    const float* __restrict__ means, const float* __restrict__ y,
    float* __restrict__ outn, float* __restrict__ dout, float* __restrict__ loss) {
  int idx = blockIdx.x * 256 + threadIdx.x;
  int tid = threadIdx.x;
  int c = idx & 63;
  int bt = idx >> 6;
  int t = bt % TT, b = bt / TT;
  float al = alphaPtr[0];
  float val = P[idx] + P[OUTN + idx] + P[2 * (size_t)OUTN + idx] + P[3 * (size_t)OUTN + idx];
  float on = R[idx] - al * val;
  outn[idx] = on;
  float od = on * stdev[b * CIN + c] + means[b * CIN + c];
  dout[idx] = od;
  float diff = fabsf(od - y[((size_t)b * 240 + 48 + t) * CIN + c]);
  __shared__ float red[256];
  red[tid] = diff;
  __syncthreads();
  if (tid < 128) red[tid] += red[tid + 128];
  __syncthreads();
  if (tid < 64) red[tid] += red[tid + 64];
  __syncthreads();
  if (tid < 64) {
    float rv = red[tid];
    #pragma unroll
    for (int s = 32; s > 0; s >>= 1) rv += __shfl_down(rv, s);
    if (tid == 0) atomicAdd(loss, rv);
  }
}

// ---------------- host launch ----------------
extern "C" void kernel_launch(void* const* d_in, const int* in_sizes, int n_in, void* d_out,
                              int out_size, void* d_ws, size_t ws_size, hipStream_t stream) {
  const float* x_enc = (const float*)d_in[0];
  const float* batch_y = (const float*)d_in[2];
  const float* y_mark = (const float*)d_in[3];
  const float* hx_init = (const float*)d_in[4];
  const float* conv_w = (const float*)d_in[5];
  const float* tf_w = (const float*)d_in[6];
  const float* Wq = (const float*)d_in[7];
  const float* Wk = (const float*)d_in[8];
  const float* Wv = (const float*)d_in[9];
  const float* Wo = (const float*)d_in[10];
  const float* bq = (const float*)d_in[11];
  const float* bk = (const float*)d_in[12];
  const float* bv = (const float*)d_in[13];
  const float* bo = (const float*)d_in[14];
  const float* ln1_g = (const float*)d_in[15];
  const float* ln1_b = (const float*)d_in[16];
  const float* W1 = (const float*)d_in[17];
  const float* b1 = (const float*)d_in[18];
  const float* W2 = (const float*)d_in[19];
  const float* b2 = (const float*)d_in[20];
  const float* ln2_g = (const float*)d_in[21];
  const float* ln2_b = (const float*)d_in[22];
  const float* pl1_w = (const float*)d_in[23];
  const float* pl1_b = (const float*)d_in[24];
  const float* pl2_w = (const float*)d_in[25];
  const float* pl2_b = (const float*)d_in[26];
  const float* proj_w = (const float*)d_in[27];
  const float* proj_b = (const float*)d_in[28];
  const float* gru_wih = (const float*)d_in[29];
  const float* gru_whh = (const float*)d_in[30];
  const float* gru_bih = (const float*)d_in[31];
  const float* gru_bhh = (const float*)d_in[32];
  const float* score_w = (const float*)d_in[33];
  const float* alpha = (const float*)d_in[34];
  float* dout = (float*)d_out;

  float* W = (float*)d_ws;
  size_t off = 0;
  float* means = W + off;   off += 2048;
  float* stdev = W + off;   off += 2048;
  float* lossacc = W + off; off += 64;
  float* preA = W + off;    off += (size_t)OUTN;
  float* outA = W + off;    off += (size_t)OUTN;
  float* outB = W + off;    off += (size_t)OUTN;
  float* corrupt = W + off; off += (size_t)OUTN;
  float* peT = W + off;     off += (size_t)TT * DM;   // PE table
  float* Wemb = W + off;    off += (size_t)KEMB * DM; // embed GEMM weights (persist)
  float* axp = W + off;     off += (size_t)4 * OUTN;  // K-split AXPY partials
  signed char* whhJ = (signed char*)(W + off); off += 786432 / 4;
  float* sws = W + off;     off += 1536;
  unsigned long long* hqg = (unsigned long long*)(W + off); off += 2 * BATCH * 128 * 2;  // 8192 qwords
  float* emb = W + off;     off += MND;
  float* Kb = W + off;      off += 2 * MND;  // 2 K-split partials for O-proj / FF2
  float* gi_all = W + off;  off += (size_t)BATCH * TT * 1536;
  unsigned short* embB = (unsigned short*)(W + off);  off += MND / 2;
  unsigned short* qkvB = (unsigned short*)(W + off);  off += (size_t)BATCH * TT * 1536 / 2;
  unsigned short* attnOB = (unsigned short*)(W + off); off += MND / 2;
  unsigned short* FFbB = (unsigned short*)(W + off);  off += (size_t)BATCH * TT * DFF / 2;
  unsigned short* xcatB = (unsigned short*)(W + off); off += (size_t)BATCH * TT * 128 / 2;
  float* bqkv = W + off;    off += 2 * 1536;
  unsigned short* WxProjB = (unsigned short*)(W + off); off += (size_t)128 * 1536 / 2;
  unsigned short* wT = (unsigned short*)(W + off);
  const size_t SQ = (size_t)DM * DM;
  const size_t SFF = (size_t)DM * DFF;
  const size_t LAYER = 4 * SQ + 2 * SFF;
  unsigned short* wihB = wT + 2 * LAYER;
  off += (2 * LAYER + (size_t)1536 * 128) / 2 + 64;
  unsigned short* dgiB = qkvB;  // alias: qkvB dead after attention, reused for dgi

  const int M = BATCH * TT;  // 6144

  // merged setup: pe/wemb/wxproj/wih/concat/hqg-zero/whh-pack/stats/loss-zero (1 launch)
  setup_misc_kernel<<<SB8 / 256, 256, 0, stream>>>(
      conv_w, tf_w, gru_wih, bq, bk, bv, gru_whh, x_enc, peT, Wemb, WxProjB, wihB, bqkv,
      hqg, whhJ, sws, means, stdev, lossacc);
  pl1_kernel<<<dim3(TT, BATCH), 64, 0, stream>>>(x_enc, means, stdev, pl1_w, pl1_b, preA);
  // merged weight transpose-pack: all 12 matrices (1 launch, 1536 blocks)
  pack_all_weights_kernel<<<1536, 256, 0, stream>>>(Wq, Wk, Wv, Wo, W1, W2, wT);

  const float* pre = preA;
  float* outs[2] = {outA, outB};
  for (int s = 0; s < 2; s++) {
    pl2_kernel<<<dim3(TT, BATCH), 64, 0, stream>>>(pre, pl2_w, pl2_b, corrupt, xcatB);
    // embed as GEMM with direct circular-gather A (build_xp eliminated)
    gemm_kernel<0, 0, 0, 1><<<dim3(DM / 64, M / 64), 256, 0, stream>>>(
        corrupt, Wemb, nullptr, emb, nullptr, peT, embB, y_mark, M, DM, KEMB);
    for (int l = 0; l < 2; l++) {
      unsigned short* base = wT + (size_t)l * LAYER;
      gemm_bf16_kernel<0, 0, 1, 0><<<dim3(1536 / 128, M / 128), 256, 0, stream>>>(
          embB, base, bqkv + l * 1536, nullptr, qkvB, M, 1536, DM);
      attention_mfma_kernel<<<dim3(NH, BATCH), 768, 0, stream>>>(qkvB, attnOB);
      // O-proj: K-split x2 partials (384 blocks), bias folded into LN
      gemm_bf16_kernel<0, 0, 0, 1><<<dim3(DM / 128, M / 128, 2), 256, 0, stream>>>(
          attnOB, base + 3 * SQ, nullptr, Kb, nullptr, M, DM, DM);
      ln_residual_ks_kernel<<<M, 256, 0, stream>>>(emb, Kb, bo + l * DM, ln1_g + l * DM,
                                                   ln1_b + l * DM, embB);
      gemm_bf16_kernel<1, 0, 1, 0><<<dim3(DFF / 128, M / 128), 256, 0, stream>>>(
          embB, base + 4 * SQ, b1 + l * DFF, nullptr, FFbB, M, DFF, DM);
      // FF2: K-split x2 (K=2048 -> 1024 each, 384 blocks)
      gemm_bf16_kernel<0, 0, 0, 1><<<dim3(DM / 128, M / 128, 2), 256, 0, stream>>>(
          FFbB, base + 4 * SQ + SFF, nullptr, Kb, nullptr, M, DM, DFF);
      ln_residual_ks_kernel<<<M, 256, 0, stream>>>(emb, Kb, b2 + l * DM, ln2_g + l * DM,
                                                   ln2_b + l * DM, embB);
    }
    // proj: writes cond bf16 straight into xcatB[:,64:128]
    gemm_kernel<1, 0, 1, 0><<<dim3(CIN / 64, M / 64), 256, 0, stream>>>(
        emb, proj_w, proj_b, nullptr, xcatB, nullptr, nullptr, nullptr, M, CIN, DM);
    gemm_bf16_kernel<0, 1, 0, 0><<<dim3(1536 / 128, M / 128), 256, 0, stream>>>(
        xcatB, wihB, gru_bih, gi_all, nullptr, M, 1536, 128);
    langevin_scan_kernel<<<dim3(BATCH, 4), 1024, 0, stream>>>(
        gi_all, hx_init + (size_t)s * BATCH * DM, whhJ, sws, gru_bhh, score_w, dgiB, hqg,
        s * TT);
    // out = xi - alpha * dgi @ Wx^T : K-split partials (192 blocks) + fused epilogue
    axpy_partial_kernel<<<dim3(4, M / 128), 256, 0, stream>>>(dgiB, WxProjB, axp, M, 1536);
    denorm_loss_fused_kernel<<<OUTN / 256, 256, 0, stream>>>(
        axp, corrupt, alpha, stdev, means, batch_y, outs[s], dout, lossacc);
    pre = outs[s];
  }
  finalize_kernel<<<1, 1, 0, stream>>>(dout, lossacc);
}